// Round 1
// baseline (1053.098 us; speedup 1.0000x reference)
//
#include <hip/hip_runtime.h>
#include <math.h>

#define BB 2
#define SS 2048
#define DD 1024
#define HH 16
#define HDD 64

// ---------------- SGEMM: C[M,N] = A[M,K] * B[K,N], fp32 row-major ----------
template <int BM, int BN, int BK>
__global__ __launch_bounds__(256) void sgemm_kernel(const float* __restrict__ A,
                                                    const float* __restrict__ Bm,
                                                    float* __restrict__ C,
                                                    int M, int N, int K) {
  constexpr int TM = BM / 16;
  constexpr int TN = BN / 16;
  __shared__ __align__(16) float As[BK][BM + 4];
  __shared__ __align__(16) float Bs[BK][BN + 4];
  const int t  = threadIdx.x;
  const int tx = t & 15;
  const int ty = t >> 4;
  const int bm = blockIdx.y * BM;
  const int bn = blockIdx.x * BN;

  float acc[TM][TN];
#pragma unroll
  for (int i = 0; i < TM; ++i)
#pragma unroll
    for (int j = 0; j < TN; ++j) acc[i][j] = 0.f;

  for (int k0 = 0; k0 < K; k0 += BK) {
    // stage A tile (BM x BK), transposed into As[k][m]
    constexpr int AV = BM * BK / (4 * 256);
#pragma unroll
    for (int u = 0; u < AV; ++u) {
      int f   = t + u * 256;
      int row = f / (BK / 4);
      int c4  = (f % (BK / 4)) * 4;
      const float4 v = *(const float4*)&A[(size_t)(bm + row) * K + k0 + c4];
      As[c4 + 0][row] = v.x;
      As[c4 + 1][row] = v.y;
      As[c4 + 2][row] = v.z;
      As[c4 + 3][row] = v.w;
    }
    // stage B tile (BK x BN)
    constexpr int BV = BK * BN / (4 * 256);
#pragma unroll
    for (int u = 0; u < BV; ++u) {
      int f   = t + u * 256;
      int row = f / (BN / 4);
      int c4  = (f % (BN / 4)) * 4;
      *(float4*)&Bs[row][c4] = *(const float4*)&Bm[(size_t)(k0 + row) * N + bn + c4];
    }
    __syncthreads();
#pragma unroll
    for (int kk = 0; kk < BK; ++kk) {
      float a[TM], b[TN];
#pragma unroll
      for (int u = 0; u < TM; u += 4) {
        float4 v = *(const float4*)&As[kk][ty * TM + u];
        a[u] = v.x; a[u + 1] = v.y; a[u + 2] = v.z; a[u + 3] = v.w;
      }
#pragma unroll
      for (int u = 0; u < TN; u += 4) {
        float4 v = *(const float4*)&Bs[kk][tx * TN + u];
        b[u] = v.x; b[u + 1] = v.y; b[u + 2] = v.z; b[u + 3] = v.w;
      }
#pragma unroll
      for (int i = 0; i < TM; ++i)
#pragma unroll
        for (int j = 0; j < TN; ++j) acc[i][j] += a[i] * b[j];
    }
    __syncthreads();
  }
#pragma unroll
  for (int i = 0; i < TM; ++i) {
    size_t roff = (size_t)(bm + ty * TM + i) * N + bn + tx * TN;
#pragma unroll
    for (int u = 0; u < TN; u += 4) {
      float4 v = {acc[i][u], acc[i][u + 1], acc[i][u + 2], acc[i][u + 3]};
      *(float4*)&C[roff + u] = v;
    }
  }
}

// -------- RoPE + split qkv[B,S,3D] -> Q/K/V [B,H,S,HD] (head-major) --------
__global__ __launch_bounds__(256) void rope_split_kernel(
    const float* __restrict__ qkv,
    const float* __restrict__ sin_q, const float* __restrict__ cos_q,
    const float* __restrict__ sin_k, const float* __restrict__ cos_k,
    float* __restrict__ Qh, float* __restrict__ Kh, float* __restrict__ Vh) {
  int idx = blockIdx.x * 256 + threadIdx.x;  // total = B*S*H*32 = 2^21
  const int total = BB * SS * HH * (HDD / 2);
  if (idx >= total) return;
  const int dp = idx & 31;
  const int h  = (idx >> 5) & (HH - 1);
  const int s  = (idx >> 9) & (SS - 1);
  const int b  = idx >> 20;

  const float* row = qkv + (size_t)(b * SS + s) * (3 * DD);
  const size_t off = ((size_t)(b * HH + h) * SS + s) * HDD + dp;

  // Q with RoPE
  {
    float c1 = cos_q[s * HDD + dp],      s1 = sin_q[s * HDD + dp];
    float c2 = cos_q[s * HDD + dp + 32], s2 = sin_q[s * HDD + dp + 32];
    float x1 = row[h * HDD + dp], x2 = row[h * HDD + dp + 32];
    Qh[off]      = x1 * c1 - x2 * s1;
    Qh[off + 32] = x2 * c2 + x1 * s2;
  }
  // K with RoPE
  {
    float c1 = cos_k[s * HDD + dp],      s1 = sin_k[s * HDD + dp];
    float c2 = cos_k[s * HDD + dp + 32], s2 = sin_k[s * HDD + dp + 32];
    float x1 = row[DD + h * HDD + dp], x2 = row[DD + h * HDD + dp + 32];
    Kh[off]      = x1 * c1 - x2 * s1;
    Kh[off + 32] = x2 * c2 + x1 * s2;
  }
  // V passthrough
  Vh[off]      = row[2 * DD + h * HDD + dp];
  Vh[off + 32] = row[2 * DD + h * HDD + dp + 32];
}

// ------------- causal flash attention, fp32, 64x64 tiles -------------------
__global__ __launch_bounds__(256) void attn_kernel(const float* __restrict__ Qh,
                                                   const float* __restrict__ Kh,
                                                   const float* __restrict__ Vh,
                                                   float* __restrict__ Oh) {
  constexpr int QB = 64, KB = 64;
  __shared__ __align__(16) float Qs[HDD][QB + 4];  // [hd][r], pre-scaled
  __shared__ __align__(16) float Ks[HDD][KB + 4];  // [hd][c]
  __shared__ __align__(16) float Vs[KB][HDD + 4];  // [c][hd]
  __shared__ __align__(16) float Ps[QB][KB + 4];   // [r][c]

  const int t  = threadIdx.x;
  const int tx = t & 15;
  const int ty = t >> 4;
  const int qi = (int)gridDim.x - 1 - (int)blockIdx.x;  // long blocks first
  const int bh = blockIdx.y;
  const int b  = bh / HH;
  const int h  = bh % HH;

  const float* Qp    = Qh + ((size_t)bh * SS + qi * QB) * HDD;
  const float* Kbase = Kh + (size_t)bh * SS * HDD;
  const float* Vbase = Vh + (size_t)bh * SS * HDD;

  // load Q tile (scaled by 1/sqrt(HD)), transposed
#pragma unroll
  for (int u = 0; u < 4; ++u) {
    int f = t + u * 256;
    int row = f >> 4;
    int c4  = (f & 15) * 4;
    float4 v = *(const float4*)&Qp[row * HDD + c4];
    Qs[c4 + 0][row] = v.x * 0.125f;
    Qs[c4 + 1][row] = v.y * 0.125f;
    Qs[c4 + 2][row] = v.z * 0.125f;
    Qs[c4 + 3][row] = v.w * 0.125f;
  }

  float m[4], l[4], o[4][4];
#pragma unroll
  for (int i = 0; i < 4; ++i) {
    m[i] = -INFINITY;
    l[i] = 0.f;
#pragma unroll
    for (int j = 0; j < 4; ++j) o[i][j] = 0.f;
  }

  __syncthreads();

  for (int kt = 0; kt <= qi; ++kt) {
    const float* Kp = Kbase + (size_t)kt * KB * HDD;
    const float* Vp = Vbase + (size_t)kt * KB * HDD;
    float4 kreg[4], vreg[4];
#pragma unroll
    for (int u = 0; u < 4; ++u) {
      int f = t + u * 256;
      int row = f >> 4;
      int c4  = (f & 15) * 4;
      kreg[u] = *(const float4*)&Kp[row * HDD + c4];
      vreg[u] = *(const float4*)&Vp[row * HDD + c4];
    }
    __syncthreads();  // previous tile's consumers done
#pragma unroll
    for (int u = 0; u < 4; ++u) {
      int f = t + u * 256;
      int row = f >> 4;
      int c4  = (f & 15) * 4;
      Ks[c4 + 0][row] = kreg[u].x;
      Ks[c4 + 1][row] = kreg[u].y;
      Ks[c4 + 2][row] = kreg[u].z;
      Ks[c4 + 3][row] = kreg[u].w;
      *(float4*)&Vs[row][c4] = vreg[u];
    }
    __syncthreads();

    // scores: sc[i][j] = sum_hd Qs[hd][ty*4+i] * Ks[hd][tx*4+j]
    float sc[4][4];
#pragma unroll
    for (int i = 0; i < 4; ++i)
#pragma unroll
      for (int j = 0; j < 4; ++j) sc[i][j] = 0.f;
#pragma unroll
    for (int kk = 0; kk < HDD; ++kk) {
      float4 av = *(const float4*)&Qs[kk][ty * 4];
      float4 bv = *(const float4*)&Ks[kk][tx * 4];
      float a[4] = {av.x, av.y, av.z, av.w};
      float bq[4] = {bv.x, bv.y, bv.z, bv.w};
#pragma unroll
      for (int i = 0; i < 4; ++i)
#pragma unroll
        for (int j = 0; j < 4; ++j) sc[i][j] += a[i] * bq[j];
    }

    if (kt == qi) {  // diagonal tile: causal mask (same tile-local offsets)
#pragma unroll
      for (int i = 0; i < 4; ++i)
#pragma unroll
        for (int j = 0; j < 4; ++j)
          if (tx * 4 + j > ty * 4 + i) sc[i][j] = -INFINITY;
    }

    // online softmax (row groups of 16 lanes: same ty, tx=0..15)
#pragma unroll
    for (int i = 0; i < 4; ++i) {
      float tm = fmaxf(fmaxf(sc[i][0], sc[i][1]), fmaxf(sc[i][2], sc[i][3]));
      tm = fmaxf(tm, __shfl_xor(tm, 1));
      tm = fmaxf(tm, __shfl_xor(tm, 2));
      tm = fmaxf(tm, __shfl_xor(tm, 4));
      tm = fmaxf(tm, __shfl_xor(tm, 8));
      float mnew = fmaxf(m[i], tm);
      float corr = __expf(m[i] - mnew);
      float p0 = __expf(sc[i][0] - mnew);
      float p1 = __expf(sc[i][1] - mnew);
      float p2 = __expf(sc[i][2] - mnew);
      float p3 = __expf(sc[i][3] - mnew);
      float4 pv = {p0, p1, p2, p3};
      *(float4*)&Ps[ty * 4 + i][tx * 4] = pv;
      float rs = p0 + p1 + p2 + p3;
      rs += __shfl_xor(rs, 1);
      rs += __shfl_xor(rs, 2);
      rs += __shfl_xor(rs, 4);
      rs += __shfl_xor(rs, 8);
      l[i] = l[i] * corr + rs;
      m[i] = mnew;
      o[i][0] *= corr; o[i][1] *= corr; o[i][2] *= corr; o[i][3] *= corr;
    }
    __syncthreads();

    // PV: o[i][j] += sum_c Ps[r][c] * Vs[c][d]
#pragma unroll 4
    for (int c4 = 0; c4 < KB / 4; ++c4) {
      float vr[4][4];
#pragma unroll
      for (int cj = 0; cj < 4; ++cj) {
        float4 vv = *(const float4*)&Vs[c4 * 4 + cj][tx * 4];
        vr[cj][0] = vv.x; vr[cj][1] = vv.y; vr[cj][2] = vv.z; vr[cj][3] = vv.w;
      }
#pragma unroll
      for (int i = 0; i < 4; ++i) {
        float4 pv = *(const float4*)&Ps[ty * 4 + i][c4 * 4];
        float pa[4] = {pv.x, pv.y, pv.z, pv.w};
#pragma unroll
        for (int cj = 0; cj < 4; ++cj)
#pragma unroll
          for (int j = 0; j < 4; ++j) o[i][j] += pa[cj] * vr[cj][j];
      }
    }
  }

  // epilogue: write O in [B,S,D] layout (transpose fused into the store)
  const size_t orow_base = ((size_t)b * SS + (size_t)qi * QB) * DD + h * HDD;
#pragma unroll
  for (int i = 0; i < 4; ++i) {
    float inv = 1.f / l[i];
    float4 v = {o[i][0] * inv, o[i][1] * inv, o[i][2] * inv, o[i][3] * inv};
    *(float4*)&Oh[orow_base + (size_t)(ty * 4 + i) * DD + tx * 4] = v;
  }
}

extern "C" void kernel_launch(void* const* d_in, const int* in_sizes, int n_in,
                              void* d_out, int out_size, void* d_ws, size_t ws_size,
                              hipStream_t stream) {
  const float* query = (const float*)d_in[0];
  const float* sin_q = (const float*)d_in[1];
  const float* cos_q = (const float*)d_in[2];
  const float* sin_k = (const float*)d_in[3];
  const float* cos_k = (const float*)d_in[4];
  const float* w_in  = (const float*)d_in[5];
  const float* w_out = (const float*)d_in[6];
  float* out = (float*)d_out;

  float* qkv = (float*)d_ws;                       // [B*S, 3D]
  const size_t qkv_elems = (size_t)BB * SS * 3 * DD;
  const size_t bh_elems  = (size_t)BB * HH * SS * HDD;
  float* Qh = qkv + qkv_elems;                     // [B,H,S,HD]
  float* Kh = Qh + bh_elems;
  float* Vh = Kh + bh_elems;
  float* Oh = Vh + bh_elems;                       // [B,S,D]

  const int M = BB * SS;  // 4096

  {  // 1) fused QKV projection
    dim3 grid((3 * DD) / 128, M / 128);
    sgemm_kernel<128, 128, 16><<<grid, 256, 0, stream>>>(query, w_in, qkv, M, 3 * DD, DD);
  }
  {  // 2) RoPE + head split
    int total = BB * SS * HH * (HDD / 2);
    rope_split_kernel<<<(total + 255) / 256, 256, 0, stream>>>(
        qkv, sin_q, cos_q, sin_k, cos_k, Qh, Kh, Vh);
  }
  {  // 3) causal attention
    dim3 grid(SS / 64, BB * HH);
    attn_kernel<<<grid, 256, 0, stream>>>(Qh, Kh, Vh, Oh);
  }
  {  // 4) output projection
    dim3 grid(DD / 128, M / 128);
    sgemm_kernel<128, 128, 16><<<grid, 256, 0, stream>>>(Oh, w_out, out, M, DD, DD);
  }
}

// Round 2
// 769.389 us; speedup vs baseline: 1.3687x; 1.3687x over previous
//
#include <hip/hip_runtime.h>
#include <hip/hip_bf16.h>
#include <math.h>

#define BB 2
#define SS 2048
#define DD 1024
#define HH 16
#define HDD 64

typedef float f32x4 __attribute__((ext_vector_type(4)));
typedef short s16x8 __attribute__((ext_vector_type(8)));

__device__ inline unsigned short f2bf(float x) {
  unsigned u = __float_as_uint(x);
  unsigned r = u + 0x7fff + ((u >> 16) & 1);  // RNE
  return (unsigned short)(r >> 16);
}
__device__ inline float bf2f(unsigned short h) {
  return __uint_as_float(((unsigned)h) << 16);
}

// ---------------- pre-pass: split fp32 -> bf16 hi/lo (no transpose) --------
__global__ __launch_bounds__(256) void split_kernel(const float* __restrict__ X,
                                                    unsigned short* __restrict__ Xh,
                                                    unsigned short* __restrict__ Xl,
                                                    int n4) {
  int i = blockIdx.x * 256 + threadIdx.x;
  if (i >= n4) return;
  float4 v = ((const float4*)X)[i];
  ushort4 h, l;
  h.x = f2bf(v.x); l.x = f2bf(v.x - bf2f(h.x));
  h.y = f2bf(v.y); l.y = f2bf(v.y - bf2f(h.y));
  h.z = f2bf(v.z); l.z = f2bf(v.z - bf2f(h.z));
  h.w = f2bf(v.w); l.w = f2bf(v.w - bf2f(h.w));
  ((ushort4*)Xh)[i] = h;
  ((ushort4*)Xl)[i] = l;
}

// -------- pre-pass: split + transpose W[K][N] -> WT_h/WT_l [N][K] ----------
__global__ __launch_bounds__(256) void split_transpose_kernel(
    const float* __restrict__ W, unsigned short* __restrict__ WTh,
    unsigned short* __restrict__ WTl, int K, int N) {
  __shared__ float tile[64][65];
  const int k0 = blockIdx.y * 64, n0 = blockIdx.x * 64;
  const int t = threadIdx.x;
  const int c = t & 63, rq = t >> 6;
#pragma unroll
  for (int u = 0; u < 16; ++u) {
    int r = u * 4 + rq;
    tile[r][c] = W[(size_t)(k0 + r) * N + n0 + c];
  }
  __syncthreads();
#pragma unroll
  for (int u = 0; u < 16; ++u) {
    int nl = u * 4 + rq;
    float v = tile[c][nl];  // = W[k0+c][n0+nl]
    unsigned short h = f2bf(v);
    unsigned short l = f2bf(v - bf2f(h));
    size_t o = (size_t)(n0 + nl) * K + k0 + c;
    WTh[o] = h;
    WTl[o] = l;
  }
}

// ---------------- bf16x3 MFMA GEMM: C[M,N] = A[M,K] * B[K,N] ---------------
// A given as hi/lo bf16 [M][K]; B given pre-transposed hi/lo bf16 [N][K].
#define GLDS16(g, l)                                                        \
  __builtin_amdgcn_global_load_lds(                                         \
      (const __attribute__((address_space(1))) unsigned int*)(const void*)(g), \
      (__attribute__((address_space(3))) unsigned int*)(l), 16, 0, 0)

__global__ __launch_bounds__(256) void gemm_bf16x3_kernel(
    const unsigned short* __restrict__ Ah, const unsigned short* __restrict__ Al,
    const unsigned short* __restrict__ BTh, const unsigned short* __restrict__ BTl,
    float* __restrict__ C, int M, int N, int K) {
  __shared__ __align__(16) unsigned short As_h[128 * 64];
  __shared__ __align__(16) unsigned short As_l[128 * 64];
  __shared__ __align__(16) unsigned short Bs_h[128 * 64];
  __shared__ __align__(16) unsigned short Bs_l[128 * 64];

  const int t = threadIdx.x;
  const int bm = blockIdx.y * 128;
  const int bn = blockIdx.x * 128;
  const int w = t >> 6, lane = t & 63;
  const int wrow = (w >> 1) * 64, wcol = (w & 1) * 64;

  // staging map: linear LDS dest (16B per thread-chunk), inverse-swizzled
  // global source so that read-side XOR-swizzle sees the right data (rule #21)
  int tp[4], ldsoff[4];
  const unsigned short* pAh[4];
  const unsigned short* pAl[4];
  const unsigned short* pBh[4];
  const unsigned short* pBl[4];
#pragma unroll
  for (int cc = 0; cc < 4; ++cc) {
    tp[cc] = t + cc * 256;               // 0..1023
    int srow = tp[cc] >> 3;              // 0..127 (8 quads/row: 64 bf16 = 128B)
    int q = tp[cc] & 7;
    int gq = q ^ (srow & 7);             // inverse swizzle on the SOURCE
    ldsoff[cc] = tp[cc] * 8;             // ushort index (= byte/2)
    pAh[cc] = Ah + (size_t)(bm + srow) * K + gq * 8;
    pAl[cc] = Al + (size_t)(bm + srow) * K + gq * 8;
    pBh[cc] = BTh + (size_t)(bn + srow) * K + gq * 8;
    pBl[cc] = BTl + (size_t)(bn + srow) * K + gq * 8;
  }

  f32x4 acc[4][4];
  const f32x4 z = {0.f, 0.f, 0.f, 0.f};
#pragma unroll
  for (int m = 0; m < 4; ++m)
#pragma unroll
    for (int n = 0; n < 4; ++n) acc[m][n] = z;

  for (int k0 = 0; k0 < K; k0 += 64) {
    __syncthreads();  // previous iter's fragment reads complete
#pragma unroll
    for (int cc = 0; cc < 4; ++cc) {
      GLDS16(pAh[cc] + k0, &As_h[ldsoff[cc]]);
      GLDS16(pAl[cc] + k0, &As_l[ldsoff[cc]]);
      GLDS16(pBh[cc] + k0, &Bs_h[ldsoff[cc]]);
      GLDS16(pBl[cc] + k0, &Bs_l[ldsoff[cc]]);
    }
    __syncthreads();  // drains vmcnt (compiler emits waitcnt before barrier)

#pragma unroll
    for (int ks = 0; ks < 2; ++ks) {
      const int kq = ks * 4 + (lane >> 4);
      const int sw = (kq ^ (lane & 7)) * 8;  // T2 XOR-swizzled quad
      s16x8 ah[4], al[4], bh[4], bl[4];
#pragma unroll
      for (int m = 0; m < 4; ++m) {
        int row = wrow + m * 16 + (lane & 15);
        int idx = row * 64 + sw;
        ah[m] = *(const s16x8*)&As_h[idx];
        al[m] = *(const s16x8*)&As_l[idx];
      }
#pragma unroll
      for (int n = 0; n < 4; ++n) {
        int row = wcol + n * 16 + (lane & 15);
        int idx = row * 64 + sw;
        bh[n] = *(const s16x8*)&Bs_h[idx];
        bl[n] = *(const s16x8*)&Bs_l[idx];
      }
#pragma unroll
      for (int m = 0; m < 4; ++m)
#pragma unroll
        for (int n = 0; n < 4; ++n) {
          acc[m][n] = __builtin_amdgcn_mfma_f32_16x16x32_bf16(ah[m], bh[n], acc[m][n], 0, 0, 0);
          acc[m][n] = __builtin_amdgcn_mfma_f32_16x16x32_bf16(ah[m], bl[n], acc[m][n], 0, 0, 0);
          acc[m][n] = __builtin_amdgcn_mfma_f32_16x16x32_bf16(al[m], bh[n], acc[m][n], 0, 0, 0);
        }
    }
  }

  // epilogue: C/D layout col=lane&15, row=(lane>>4)*4+r  [m89 verified]
#pragma unroll
  for (int m = 0; m < 4; ++m)
#pragma unroll
    for (int n = 0; n < 4; ++n) {
      f32x4 v = acc[m][n];
      int col = bn + wcol + n * 16 + (lane & 15);
      int row0 = bm + wrow + m * 16 + (lane >> 4) * 4;
#pragma unroll
      for (int r = 0; r < 4; ++r) C[(size_t)(row0 + r) * N + col] = v[r];
    }
}

// -------- RoPE + split qkv[B,S,3D] -> Q/K/V [B,H,S,HD] (head-major) --------
__global__ __launch_bounds__(256) void rope_split_kernel(
    const float* __restrict__ qkv,
    const float* __restrict__ sin_q, const float* __restrict__ cos_q,
    const float* __restrict__ sin_k, const float* __restrict__ cos_k,
    float* __restrict__ Qh, float* __restrict__ Kh, float* __restrict__ Vh) {
  int idx = blockIdx.x * 256 + threadIdx.x;
  const int total = BB * SS * HH * (HDD / 2);
  if (idx >= total) return;
  const int dp = idx & 31;
  const int h  = (idx >> 5) & (HH - 1);
  const int s  = (idx >> 9) & (SS - 1);
  const int b  = idx >> 20;

  const float* row = qkv + (size_t)(b * SS + s) * (3 * DD);
  const size_t off = ((size_t)(b * HH + h) * SS + s) * HDD + dp;

  {
    float c1 = cos_q[s * HDD + dp],      s1 = sin_q[s * HDD + dp];
    float c2 = cos_q[s * HDD + dp + 32], s2 = sin_q[s * HDD + dp + 32];
    float x1 = row[h * HDD + dp], x2 = row[h * HDD + dp + 32];
    Qh[off]      = x1 * c1 - x2 * s1;
    Qh[off + 32] = x2 * c2 + x1 * s2;
  }
  {
    float c1 = cos_k[s * HDD + dp],      s1 = sin_k[s * HDD + dp];
    float c2 = cos_k[s * HDD + dp + 32], s2 = sin_k[s * HDD + dp + 32];
    float x1 = row[DD + h * HDD + dp], x2 = row[DD + h * HDD + dp + 32];
    Kh[off]      = x1 * c1 - x2 * s1;
    Kh[off + 32] = x2 * c2 + x1 * s2;
  }
  Vh[off]      = row[2 * DD + h * HDD + dp];
  Vh[off + 32] = row[2 * DD + h * HDD + dp + 32];
}

// ------------- causal flash attention, fp32, 64x64 tiles (unchanged) -------
__global__ __launch_bounds__(256) void attn_kernel(const float* __restrict__ Qh,
                                                   const float* __restrict__ Kh,
                                                   const float* __restrict__ Vh,
                                                   float* __restrict__ Oh) {
  constexpr int QB = 64, KB = 64;
  __shared__ __align__(16) float Qs[HDD][QB + 4];
  __shared__ __align__(16) float Ks[HDD][KB + 4];
  __shared__ __align__(16) float Vs[KB][HDD + 4];
  __shared__ __align__(16) float Ps[QB][KB + 4];

  const int t  = threadIdx.x;
  const int tx = t & 15;
  const int ty = t >> 4;
  const int qi = (int)gridDim.x - 1 - (int)blockIdx.x;
  const int bh = blockIdx.y;
  const int b  = bh / HH;
  const int h  = bh % HH;

  const float* Qp    = Qh + ((size_t)bh * SS + qi * QB) * HDD;
  const float* Kbase = Kh + (size_t)bh * SS * HDD;
  const float* Vbase = Vh + (size_t)bh * SS * HDD;

#pragma unroll
  for (int u = 0; u < 4; ++u) {
    int f = t + u * 256;
    int row = f >> 4;
    int c4  = (f & 15) * 4;
    float4 v = *(const float4*)&Qp[row * HDD + c4];
    Qs[c4 + 0][row] = v.x * 0.125f;
    Qs[c4 + 1][row] = v.y * 0.125f;
    Qs[c4 + 2][row] = v.z * 0.125f;
    Qs[c4 + 3][row] = v.w * 0.125f;
  }

  float m[4], l[4], o[4][4];
#pragma unroll
  for (int i = 0; i < 4; ++i) {
    m[i] = -INFINITY;
    l[i] = 0.f;
#pragma unroll
    for (int j = 0; j < 4; ++j) o[i][j] = 0.f;
  }

  __syncthreads();

  for (int kt = 0; kt <= qi; ++kt) {
    const float* Kp = Kbase + (size_t)kt * KB * HDD;
    const float* Vp = Vbase + (size_t)kt * KB * HDD;
    float4 kreg[4], vreg[4];
#pragma unroll
    for (int u = 0; u < 4; ++u) {
      int f = t + u * 256;
      int row = f >> 4;
      int c4  = (f & 15) * 4;
      kreg[u] = *(const float4*)&Kp[row * HDD + c4];
      vreg[u] = *(const float4*)&Vp[row * HDD + c4];
    }
    __syncthreads();
#pragma unroll
    for (int u = 0; u < 4; ++u) {
      int f = t + u * 256;
      int row = f >> 4;
      int c4  = (f & 15) * 4;
      Ks[c4 + 0][row] = kreg[u].x;
      Ks[c4 + 1][row] = kreg[u].y;
      Ks[c4 + 2][row] = kreg[u].z;
      Ks[c4 + 3][row] = kreg[u].w;
      *(float4*)&Vs[row][c4] = vreg[u];
    }
    __syncthreads();

    float sc[4][4];
#pragma unroll
    for (int i = 0; i < 4; ++i)
#pragma unroll
      for (int j = 0; j < 4; ++j) sc[i][j] = 0.f;
#pragma unroll
    for (int kk = 0; kk < HDD; ++kk) {
      float4 av = *(const float4*)&Qs[kk][ty * 4];
      float4 bv = *(const float4*)&Ks[kk][tx * 4];
      float a[4] = {av.x, av.y, av.z, av.w};
      float bq[4] = {bv.x, bv.y, bv.z, bv.w};
#pragma unroll
      for (int i = 0; i < 4; ++i)
#pragma unroll
        for (int j = 0; j < 4; ++j) sc[i][j] += a[i] * bq[j];
    }

    if (kt == qi) {
#pragma unroll
      for (int i = 0; i < 4; ++i)
#pragma unroll
        for (int j = 0; j < 4; ++j)
          if (tx * 4 + j > ty * 4 + i) sc[i][j] = -INFINITY;
    }

#pragma unroll
    for (int i = 0; i < 4; ++i) {
      float tm = fmaxf(fmaxf(sc[i][0], sc[i][1]), fmaxf(sc[i][2], sc[i][3]));
      tm = fmaxf(tm, __shfl_xor(tm, 1));
      tm = fmaxf(tm, __shfl_xor(tm, 2));
      tm = fmaxf(tm, __shfl_xor(tm, 4));
      tm = fmaxf(tm, __shfl_xor(tm, 8));
      float mnew = fmaxf(m[i], tm);
      float corr = __expf(m[i] - mnew);
      float p0 = __expf(sc[i][0] - mnew);
      float p1 = __expf(sc[i][1] - mnew);
      float p2 = __expf(sc[i][2] - mnew);
      float p3 = __expf(sc[i][3] - mnew);
      float4 pv = {p0, p1, p2, p3};
      *(float4*)&Ps[ty * 4 + i][tx * 4] = pv;
      float rs = p0 + p1 + p2 + p3;
      rs += __shfl_xor(rs, 1);
      rs += __shfl_xor(rs, 2);
      rs += __shfl_xor(rs, 4);
      rs += __shfl_xor(rs, 8);
      l[i] = l[i] * corr + rs;
      m[i] = mnew;
      o[i][0] *= corr; o[i][1] *= corr; o[i][2] *= corr; o[i][3] *= corr;
    }
    __syncthreads();

#pragma unroll 4
    for (int c4 = 0; c4 < KB / 4; ++c4) {
      float vr[4][4];
#pragma unroll
      for (int cj = 0; cj < 4; ++cj) {
        float4 vv = *(const float4*)&Vs[c4 * 4 + cj][tx * 4];
        vr[cj][0] = vv.x; vr[cj][1] = vv.y; vr[cj][2] = vv.z; vr[cj][3] = vv.w;
      }
#pragma unroll
      for (int i = 0; i < 4; ++i) {
        float4 pv = *(const float4*)&Ps[ty * 4 + i][c4 * 4];
        float pa[4] = {pv.x, pv.y, pv.z, pv.w};
#pragma unroll
        for (int cj = 0; cj < 4; ++cj)
#pragma unroll
          for (int j = 0; j < 4; ++j) o[i][j] += pa[cj] * vr[cj][j];
      }
    }
  }

  const size_t orow_base = ((size_t)b * SS + (size_t)qi * QB) * DD + h * HDD;
#pragma unroll
  for (int i = 0; i < 4; ++i) {
    float inv = 1.f / l[i];
    float4 v = {o[i][0] * inv, o[i][1] * inv, o[i][2] * inv, o[i][3] * inv};
    *(float4*)&Oh[orow_base + (size_t)(ty * 4 + i) * DD + tx * 4] = v;
  }
}

extern "C" void kernel_launch(void* const* d_in, const int* in_sizes, int n_in,
                              void* d_out, int out_size, void* d_ws, size_t ws_size,
                              hipStream_t stream) {
  const float* query = (const float*)d_in[0];
  const float* sin_q = (const float*)d_in[1];
  const float* cos_q = (const float*)d_in[2];
  const float* sin_k = (const float*)d_in[3];
  const float* cos_k = (const float*)d_in[4];
  const float* w_in  = (const float*)d_in[5];
  const float* w_out = (const float*)d_in[6];
  float* out = (float*)d_out;

  const int M = BB * SS;  // 4096

  unsigned char* ws = (unsigned char*)d_ws;
  size_t off = 0;
  float* qkv = (float*)(ws + off); off += (size_t)M * 3 * DD * 4;          // 48MB
  float* Qh  = (float*)(ws + off); off += (size_t)M * DD * 4;              // 16MB
  float* Kh  = (float*)(ws + off); off += (size_t)M * DD * 4;
  float* Vh  = (float*)(ws + off); off += (size_t)M * DD * 4;
  float* Oh  = (float*)(ws + off); off += (size_t)M * DD * 4;
  unsigned short* Axh = (unsigned short*)(ws + off); off += (size_t)M * DD * 2;  // reused for Oh-split
  unsigned short* Axl = (unsigned short*)(ws + off); off += (size_t)M * DD * 2;
  unsigned short* B1h = (unsigned short*)(ws + off); off += (size_t)DD * 3 * DD * 2;
  unsigned short* B1l = (unsigned short*)(ws + off); off += (size_t)DD * 3 * DD * 2;
  unsigned short* B2h = (unsigned short*)(ws + off); off += (size_t)DD * DD * 2;
  unsigned short* B2l = (unsigned short*)(ws + off); off += (size_t)DD * DD * 2;

  {  // pre-pass: operand splits (hi/lo bf16)
    int n4 = M * DD / 4;
    split_kernel<<<(n4 + 255) / 256, 256, 0, stream>>>(query, Axh, Axl, n4);
    split_transpose_kernel<<<dim3(3 * DD / 64, DD / 64), 256, 0, stream>>>(w_in, B1h, B1l, DD, 3 * DD);
    split_transpose_kernel<<<dim3(DD / 64, DD / 64), 256, 0, stream>>>(w_out, B2h, B2l, DD, DD);
  }
  {  // 1) fused QKV projection (bf16x3 MFMA)
    dim3 grid((3 * DD) / 128, M / 128);
    gemm_bf16x3_kernel<<<grid, 256, 0, stream>>>(Axh, Axl, B1h, B1l, qkv, M, 3 * DD, DD);
  }
  {  // 2) RoPE + head split
    int total = BB * SS * HH * (HDD / 2);
    rope_split_kernel<<<(total + 255) / 256, 256, 0, stream>>>(
        qkv, sin_q, cos_q, sin_k, cos_k, Qh, Kh, Vh);
  }
  {  // 3) causal attention
    dim3 grid(SS / 64, BB * HH);
    attn_kernel<<<grid, 256, 0, stream>>>(Qh, Kh, Vh, Oh);
  }
  {  // 4) output projection (split Oh, then bf16x3 MFMA)
    int n4 = M * DD / 4;
    split_kernel<<<(n4 + 255) / 256, 256, 0, stream>>>(Oh, Axh, Axl, n4);
    dim3 grid(DD / 128, M / 128);
    gemm_bf16x3_kernel<<<grid, 256, 0, stream>>>(Axh, Axl, B2h, B2l, out, M, DD, DD);
  }
}

// Round 3
// 363.706 us; speedup vs baseline: 2.8955x; 2.1154x over previous
//
#include <hip/hip_runtime.h>
#include <hip/hip_bf16.h>
#include <math.h>

#define BB 2
#define SS 2048
#define DD 1024
#define HH 16
#define HDD 64

typedef float f32x4 __attribute__((ext_vector_type(4)));
typedef short s16x8 __attribute__((ext_vector_type(8)));
typedef unsigned short u16x8 __attribute__((ext_vector_type(8)));

__device__ inline unsigned short f2bf(float x) {
  unsigned u = __float_as_uint(x);
  unsigned r = u + 0x7fff + ((u >> 16) & 1);  // RNE
  return (unsigned short)(r >> 16);
}
__device__ inline float bf2f(unsigned short h) {
  return __uint_as_float(((unsigned)h) << 16);
}

// ---------------- pre-pass: split fp32 -> bf16 hi/lo (no transpose) --------
__global__ __launch_bounds__(256) void split_kernel(const float* __restrict__ X,
                                                    unsigned short* __restrict__ Xh,
                                                    unsigned short* __restrict__ Xl,
                                                    int n4) {
  int i = blockIdx.x * 256 + threadIdx.x;
  if (i >= n4) return;
  float4 v = ((const float4*)X)[i];
  ushort4 h, l;
  h.x = f2bf(v.x); l.x = f2bf(v.x - bf2f(h.x));
  h.y = f2bf(v.y); l.y = f2bf(v.y - bf2f(h.y));
  h.z = f2bf(v.z); l.z = f2bf(v.z - bf2f(h.z));
  h.w = f2bf(v.w); l.w = f2bf(v.w - bf2f(h.w));
  ((ushort4*)Xh)[i] = h;
  ((ushort4*)Xl)[i] = l;
}

// -------- pre-pass: split + transpose W[K][N] -> WT_h/WT_l [N][K] ----------
__global__ __launch_bounds__(256) void split_transpose_kernel(
    const float* __restrict__ W, unsigned short* __restrict__ WTh,
    unsigned short* __restrict__ WTl, int K, int N) {
  __shared__ float tile[64][65];
  const int k0 = blockIdx.y * 64, n0 = blockIdx.x * 64;
  const int t = threadIdx.x;
  const int c = t & 63, rq = t >> 6;
#pragma unroll
  for (int u = 0; u < 16; ++u) {
    int r = u * 4 + rq;
    tile[r][c] = W[(size_t)(k0 + r) * N + n0 + c];
  }
  __syncthreads();
#pragma unroll
  for (int u = 0; u < 16; ++u) {
    int nl = u * 4 + rq;
    float v = tile[c][nl];  // = W[k0+c][n0+nl]
    unsigned short h = f2bf(v);
    unsigned short l = f2bf(v - bf2f(h));
    size_t o = (size_t)(n0 + nl) * K + k0 + c;
    WTh[o] = h;
    WTl[o] = l;
  }
}

// ---------------- bf16x3 MFMA GEMM: C[M,N] = A[M,K] * B[K,N] ---------------
#define GLDS16(g, l)                                                        \
  __builtin_amdgcn_global_load_lds(                                         \
      (const __attribute__((address_space(1))) unsigned int*)(const void*)(g), \
      (__attribute__((address_space(3))) unsigned int*)(l), 16, 0, 0)

__global__ __launch_bounds__(256) void gemm_bf16x3_kernel(
    const unsigned short* __restrict__ Ah, const unsigned short* __restrict__ Al,
    const unsigned short* __restrict__ BTh, const unsigned short* __restrict__ BTl,
    float* __restrict__ C, int M, int N, int K) {
  __shared__ __align__(16) unsigned short As_h[128 * 64];
  __shared__ __align__(16) unsigned short As_l[128 * 64];
  __shared__ __align__(16) unsigned short Bs_h[128 * 64];
  __shared__ __align__(16) unsigned short Bs_l[128 * 64];

  const int t = threadIdx.x;
  const int bm = blockIdx.y * 128;
  const int bn = blockIdx.x * 128;
  const int w = t >> 6, lane = t & 63;
  const int wrow = (w >> 1) * 64, wcol = (w & 1) * 64;

  int tp[4], ldsoff[4];
  const unsigned short* pAh[4];
  const unsigned short* pAl[4];
  const unsigned short* pBh[4];
  const unsigned short* pBl[4];
#pragma unroll
  for (int cc = 0; cc < 4; ++cc) {
    tp[cc] = t + cc * 256;
    int srow = tp[cc] >> 3;
    int q = tp[cc] & 7;
    int gq = q ^ (srow & 7);
    ldsoff[cc] = tp[cc] * 8;
    pAh[cc] = Ah + (size_t)(bm + srow) * K + gq * 8;
    pAl[cc] = Al + (size_t)(bm + srow) * K + gq * 8;
    pBh[cc] = BTh + (size_t)(bn + srow) * K + gq * 8;
    pBl[cc] = BTl + (size_t)(bn + srow) * K + gq * 8;
  }

  f32x4 acc[4][4];
  const f32x4 z = {0.f, 0.f, 0.f, 0.f};
#pragma unroll
  for (int m = 0; m < 4; ++m)
#pragma unroll
    for (int n = 0; n < 4; ++n) acc[m][n] = z;

  for (int k0 = 0; k0 < K; k0 += 64) {
    __syncthreads();
#pragma unroll
    for (int cc = 0; cc < 4; ++cc) {
      GLDS16(pAh[cc] + k0, &As_h[ldsoff[cc]]);
      GLDS16(pAl[cc] + k0, &As_l[ldsoff[cc]]);
      GLDS16(pBh[cc] + k0, &Bs_h[ldsoff[cc]]);
      GLDS16(pBl[cc] + k0, &Bs_l[ldsoff[cc]]);
    }
    __syncthreads();

#pragma unroll
    for (int ks = 0; ks < 2; ++ks) {
      const int kq = ks * 4 + (lane >> 4);
      const int sw = (kq ^ (lane & 7)) * 8;
      s16x8 ah[4], al[4], bh[4], bl[4];
#pragma unroll
      for (int m = 0; m < 4; ++m) {
        int row = wrow + m * 16 + (lane & 15);
        int idx = row * 64 + sw;
        ah[m] = *(const s16x8*)&As_h[idx];
        al[m] = *(const s16x8*)&As_l[idx];
      }
#pragma unroll
      for (int n = 0; n < 4; ++n) {
        int row = wcol + n * 16 + (lane & 15);
        int idx = row * 64 + sw;
        bh[n] = *(const s16x8*)&Bs_h[idx];
        bl[n] = *(const s16x8*)&Bs_l[idx];
      }
#pragma unroll
      for (int m = 0; m < 4; ++m)
#pragma unroll
        for (int n = 0; n < 4; ++n) {
          acc[m][n] = __builtin_amdgcn_mfma_f32_16x16x32_bf16(ah[m], bh[n], acc[m][n], 0, 0, 0);
          acc[m][n] = __builtin_amdgcn_mfma_f32_16x16x32_bf16(ah[m], bl[n], acc[m][n], 0, 0, 0);
          acc[m][n] = __builtin_amdgcn_mfma_f32_16x16x32_bf16(al[m], bh[n], acc[m][n], 0, 0, 0);
        }
    }
  }

#pragma unroll
  for (int m = 0; m < 4; ++m)
#pragma unroll
    for (int n = 0; n < 4; ++n) {
      f32x4 v = acc[m][n];
      int col = bn + wcol + n * 16 + (lane & 15);
      int row0 = bm + wrow + m * 16 + (lane >> 4) * 4;
#pragma unroll
      for (int r = 0; r < 4; ++r) C[(size_t)(row0 + r) * N + col] = v[r];
    }
}

// -------- RoPE + split qkv -> Qhi/Qlo (x0.125), Khi/Klo, Vb (bf16) ---------
// Layout [B,H,S,HD]
__global__ __launch_bounds__(256) void rope_split_bf16_kernel(
    const float* __restrict__ qkv,
    const float* __restrict__ sin_q, const float* __restrict__ cos_q,
    const float* __restrict__ sin_k, const float* __restrict__ cos_k,
    unsigned short* __restrict__ Qhi, unsigned short* __restrict__ Qlo,
    unsigned short* __restrict__ Khi, unsigned short* __restrict__ Klo,
    unsigned short* __restrict__ Vb) {
  int idx = blockIdx.x * 256 + threadIdx.x;
  const int total = BB * SS * HH * (HDD / 2);
  if (idx >= total) return;
  const int dp = idx & 31;
  const int h  = (idx >> 5) & (HH - 1);
  const int s  = (idx >> 9) & (SS - 1);
  const int b  = idx >> 20;

  const float* row = qkv + (size_t)(b * SS + s) * (3 * DD);
  const size_t off = ((size_t)(b * HH + h) * SS + s) * HDD + dp;

  {
    float c1 = cos_q[s * HDD + dp],      s1 = sin_q[s * HDD + dp];
    float c2 = cos_q[s * HDD + dp + 32], s2 = sin_q[s * HDD + dp + 32];
    float x1 = row[h * HDD + dp], x2 = row[h * HDD + dp + 32];
    float q1 = (x1 * c1 - x2 * s1) * 0.125f;  // fold 1/sqrt(HD), exact pow2
    float q2 = (x2 * c2 + x1 * s2) * 0.125f;
    unsigned short h1 = f2bf(q1), h2 = f2bf(q2);
    Qhi[off]      = h1; Qlo[off]      = f2bf(q1 - bf2f(h1));
    Qhi[off + 32] = h2; Qlo[off + 32] = f2bf(q2 - bf2f(h2));
  }
  {
    float c1 = cos_k[s * HDD + dp],      s1 = sin_k[s * HDD + dp];
    float c2 = cos_k[s * HDD + dp + 32], s2 = sin_k[s * HDD + dp + 32];
    float x1 = row[DD + h * HDD + dp], x2 = row[DD + h * HDD + dp + 32];
    float k1 = x1 * c1 - x2 * s1;
    float k2 = x2 * c2 + x1 * s2;
    unsigned short h1 = f2bf(k1), h2 = f2bf(k2);
    Khi[off]      = h1; Klo[off]      = f2bf(k1 - bf2f(h1));
    Khi[off + 32] = h2; Klo[off + 32] = f2bf(k2 - bf2f(h2));
  }
  Vb[off]      = f2bf(row[2 * DD + h * HDD + dp]);
  Vb[off + 32] = f2bf(row[2 * DD + h * HDD + dp + 32]);
}

// -------- V transpose: Vb [B,H,S,HD] bf16 -> Vt [B,H,HD,S] bf16 ------------
__global__ __launch_bounds__(256) void vtranspose_kernel(
    const unsigned short* __restrict__ Vb, unsigned short* __restrict__ Vt) {
  __shared__ unsigned short tile[64][72];
  const int s0 = blockIdx.x * 64;
  const int bh = blockIdx.y;
  const int t = threadIdx.x;
  const unsigned short* base = Vb + ((size_t)bh * SS + s0) * HDD;
#pragma unroll
  for (int c = 0; c < 2; ++c) {
    int G = t + c * 256;
    int r = G >> 3, g = G & 7;
    u16x8 v = *(const u16x8*)&base[r * HDD + g * 8];
    *(u16x8*)&tile[r][g * 8] = v;
  }
  __syncthreads();
#pragma unroll
  for (int c = 0; c < 2; ++c) {
    int G = t + c * 256;
    int d = G >> 3, gs = G & 7;
    u16x8 v;
#pragma unroll
    for (int j = 0; j < 8; ++j) v[j] = tile[gs * 8 + j][d];
    *(u16x8*)&Vt[((size_t)bh * HDD + d) * SS + s0 + gs * 8] = v;
  }
}

// ------------- causal flash attention, bf16 MFMA, 64x64 tiles --------------
// Q,K hi/lo split (3-MFMA QK^T: fp32-accurate scores); P,V single bf16.
__global__ __launch_bounds__(256) void attn_mfma_kernel(
    const unsigned short* __restrict__ Qhi, const unsigned short* __restrict__ Qlo,
    const unsigned short* __restrict__ Khi_g, const unsigned short* __restrict__ Klo_g,
    const unsigned short* __restrict__ Vt_g,
    unsigned short* __restrict__ Ohi, unsigned short* __restrict__ Olo) {
  __shared__ __align__(16) unsigned short Ks_h[64 * 64];
  __shared__ __align__(16) unsigned short Ks_l[64 * 64];
  __shared__ __align__(16) unsigned short Vs[64 * 64];
  __shared__ __align__(16) unsigned short Ps[64 * 72];

  const int t = threadIdx.x;
  const int lane = t & 63;
  const int w = t >> 6;
  const int qi = (int)gridDim.x - 1 - (int)blockIdx.x;  // long blocks first
  const int bh = blockIdx.y;
  const int b = bh >> 4, h = bh & 15;
  const int l15 = lane & 15, l4 = lane >> 4, l7 = lane & 7;

  // Q fragments for this wave's 16 rows (pre-scaled by 0.125 in rope pass)
  s16x8 qh[2], ql[2];
  {
    const int rowA = qi * 64 + w * 16 + l15;
    const unsigned short* qb = Qhi + ((size_t)bh * SS + rowA) * HDD + 8 * l4;
    const unsigned short* qc = Qlo + ((size_t)bh * SS + rowA) * HDD + 8 * l4;
    qh[0] = *(const s16x8*)(qb);
    qh[1] = *(const s16x8*)(qb + 32);
    ql[0] = *(const s16x8*)(qc);
    ql[1] = *(const s16x8*)(qc + 32);
  }

  // staging maps: linear LDS dest, inverse-swizzled global source (rule #21)
  int lds[2];
  size_t koff[2], voff[2];
#pragma unroll
  for (int c = 0; c < 2; ++c) {
    int G = t + c * 256;
    int row = G >> 3, g = G & 7;
    int gs = g ^ (row & 7);
    lds[c] = G * 8;  // ushort index -> byte*2 = G*16
    koff[c] = ((size_t)bh * SS + row) * HDD + gs * 8;
    voff[c] = ((size_t)bh * HDD + row) * SS + gs * 8;
  }

  f32x4 o[4];
  const f32x4 z = {0.f, 0.f, 0.f, 0.f};
#pragma unroll
  for (int n = 0; n < 4; ++n) o[n] = z;
  float m[4], lsum[4];
#pragma unroll
  for (int r = 0; r < 4; ++r) { m[r] = -INFINITY; lsum[r] = 0.f; }

  for (int kt = 0; kt <= qi; ++kt) {
    __syncthreads();  // prior tile's LDS reads done
    {
      const size_t ka = (size_t)kt * 64 * HDD;
      const size_t va = (size_t)kt * 64;
#pragma unroll
      for (int c = 0; c < 2; ++c) {
        GLDS16(Khi_g + ka + koff[c], &Ks_h[lds[c]]);
        GLDS16(Klo_g + ka + koff[c], &Ks_l[lds[c]]);
        GLDS16(Vt_g + va + voff[c], &Vs[lds[c]]);
      }
    }
    __syncthreads();  // staging drained

    // ---- QK^T (hi/lo x hi: 3 MFMAs) ----
    f32x4 sc[4];
#pragma unroll
    for (int n = 0; n < 4; ++n) sc[n] = z;
#pragma unroll
    for (int kc = 0; kc < 2; ++kc) {
      const int swz = ((kc * 4 + l4) ^ l7) * 8;
#pragma unroll
      for (int n = 0; n < 4; ++n) {
        const int idx = (n * 16 + l15) * 64 + swz;
        s16x8 kh = *(const s16x8*)&Ks_h[idx];
        s16x8 kl = *(const s16x8*)&Ks_l[idx];
        sc[n] = __builtin_amdgcn_mfma_f32_16x16x32_bf16(qh[kc], kh, sc[n], 0, 0, 0);
        sc[n] = __builtin_amdgcn_mfma_f32_16x16x32_bf16(ql[kc], kh, sc[n], 0, 0, 0);
        sc[n] = __builtin_amdgcn_mfma_f32_16x16x32_bf16(qh[kc], kl, sc[n], 0, 0, 0);
      }
    }

    if (kt == qi) {  // diagonal: causal mask (tile-local compare)
#pragma unroll
      for (int n = 0; n < 4; ++n)
#pragma unroll
        for (int r = 0; r < 4; ++r)
          if (n * 16 + l15 > w * 16 + l4 * 4 + r) sc[n][r] = -INFINITY;
    }

    // ---- online softmax (row group = 16 lanes sharing l4) ----
#pragma unroll
    for (int r = 0; r < 4; ++r) {
      float tm = fmaxf(fmaxf(sc[0][r], sc[1][r]), fmaxf(sc[2][r], sc[3][r]));
      tm = fmaxf(tm, __shfl_xor(tm, 1));
      tm = fmaxf(tm, __shfl_xor(tm, 2));
      tm = fmaxf(tm, __shfl_xor(tm, 4));
      tm = fmaxf(tm, __shfl_xor(tm, 8));
      float mn = fmaxf(m[r], tm);
      float corr = __expf(m[r] - mn);
      m[r] = mn;
      float p0 = __expf(sc[0][r] - mn);
      float p1 = __expf(sc[1][r] - mn);
      float p2 = __expf(sc[2][r] - mn);
      float p3 = __expf(sc[3][r] - mn);
      float rs = p0 + p1 + p2 + p3;
      rs += __shfl_xor(rs, 1);
      rs += __shfl_xor(rs, 2);
      rs += __shfl_xor(rs, 4);
      rs += __shfl_xor(rs, 8);
      lsum[r] = lsum[r] * corr + rs;
      o[0][r] *= corr; o[1][r] *= corr; o[2][r] *= corr; o[3][r] *= corr;
      const int pr = (w * 16 + l4 * 4 + r) * 72;
      Ps[pr + 0 * 16 + l15] = f2bf(p0);
      Ps[pr + 1 * 16 + l15] = f2bf(p1);
      Ps[pr + 2 * 16 + l15] = f2bf(p2);
      Ps[pr + 3 * 16 + l15] = f2bf(p3);
    }
    // Ps rows are wave-private: no barrier, lgkmcnt ordering suffices

    // ---- PV ----
    const int prow = (w * 16 + l15) * 72;
#pragma unroll
    for (int c = 0; c < 2; ++c) {
      s16x8 pa = *(const s16x8*)&Ps[prow + c * 32 + 8 * l4];
      const int swz = ((c * 4 + l4) ^ l7) * 8;
#pragma unroll
      for (int n = 0; n < 4; ++n) {
        s16x8 vb = *(const s16x8*)&Vs[(n * 16 + l15) * 64 + swz];
        o[n] = __builtin_amdgcn_mfma_f32_16x16x32_bf16(pa, vb, o[n], 0, 0, 0);
      }
    }
  }

  // ---- epilogue: O/l -> hi/lo bf16 in [B,S,D] ----
#pragma unroll
  for (int r = 0; r < 4; ++r) {
    const float inv = 1.f / lsum[r];
    const int orow = qi * 64 + w * 16 + l4 * 4 + r;
    const size_t ob = ((size_t)b * SS + orow) * DD + h * HDD + l15;
#pragma unroll
    for (int n = 0; n < 4; ++n) {
      float val = o[n][r] * inv;
      unsigned short hh = f2bf(val);
      Ohi[ob + n * 16] = hh;
      Olo[ob + n * 16] = f2bf(val - bf2f(hh));
    }
  }
}

extern "C" void kernel_launch(void* const* d_in, const int* in_sizes, int n_in,
                              void* d_out, int out_size, void* d_ws, size_t ws_size,
                              hipStream_t stream) {
  const float* query = (const float*)d_in[0];
  const float* sin_q = (const float*)d_in[1];
  const float* cos_q = (const float*)d_in[2];
  const float* sin_k = (const float*)d_in[3];
  const float* cos_k = (const float*)d_in[4];
  const float* w_in  = (const float*)d_in[5];
  const float* w_out = (const float*)d_in[6];
  float* out = (float*)d_out;

  const int M = BB * SS;  // 4096
  const size_t MD = (size_t)M * DD;  // 4M elements

  unsigned char* ws = (unsigned char*)d_ws;
  size_t off = 0;
  float* qkv = (float*)(ws + off); off += MD * 3 * 4;                        // 48MB
  unsigned short* Axh = (unsigned short*)(ws + off); off += MD * 2;          // 8MB
  unsigned short* Axl = (unsigned short*)(ws + off); off += MD * 2;
  unsigned short* B1h = (unsigned short*)(ws + off); off += (size_t)DD * 3 * DD * 2;
  unsigned short* B1l = (unsigned short*)(ws + off); off += (size_t)DD * 3 * DD * 2;
  unsigned short* B2h = (unsigned short*)(ws + off); off += (size_t)DD * DD * 2;
  unsigned short* B2l = (unsigned short*)(ws + off); off += (size_t)DD * DD * 2;
  unsigned short* Qhi = (unsigned short*)(ws + off); off += MD * 2;
  unsigned short* Qlo = (unsigned short*)(ws + off); off += MD * 2;
  unsigned short* Khi = (unsigned short*)(ws + off); off += MD * 2;
  unsigned short* Klo = (unsigned short*)(ws + off); off += MD * 2;
  unsigned short* Vb  = (unsigned short*)(ws + off); off += MD * 2;
  unsigned short* Vt  = (unsigned short*)(ws + off); off += MD * 2;
  unsigned short* Ohi = (unsigned short*)(ws + off); off += MD * 2;
  unsigned short* Olo = (unsigned short*)(ws + off); off += MD * 2;

  {  // pre-pass: operand splits
    int n4 = (int)(MD / 4);
    split_kernel<<<(n4 + 255) / 256, 256, 0, stream>>>(query, Axh, Axl, n4);
    split_transpose_kernel<<<dim3(3 * DD / 64, DD / 64), 256, 0, stream>>>(w_in, B1h, B1l, DD, 3 * DD);
    split_transpose_kernel<<<dim3(DD / 64, DD / 64), 256, 0, stream>>>(w_out, B2h, B2l, DD, DD);
  }
  {  // 1) fused QKV projection
    dim3 grid((3 * DD) / 128, M / 128);
    gemm_bf16x3_kernel<<<grid, 256, 0, stream>>>(Axh, Axl, B1h, B1l, qkv, M, 3 * DD, DD);
  }
  {  // 2) RoPE + split to bf16 hi/lo heads
    int total = BB * SS * HH * (HDD / 2);
    rope_split_bf16_kernel<<<(total + 255) / 256, 256, 0, stream>>>(
        qkv, sin_q, cos_q, sin_k, cos_k, Qhi, Qlo, Khi, Klo, Vb);
  }
  {  // 2b) V transpose for PV fragments
    vtranspose_kernel<<<dim3(SS / 64, BB * HH), 256, 0, stream>>>(Vb, Vt);
  }
  {  // 3) causal attention (MFMA)
    dim3 grid(SS / 64, BB * HH);
    attn_mfma_kernel<<<grid, 256, 0, stream>>>(Qhi, Qlo, Khi, Klo, Vt, Ohi, Olo);
  }
  {  // 4) output projection
    dim3 grid(DD / 128, M / 128);
    gemm_bf16x3_kernel<<<grid, 256, 0, stream>>>(Ohi, Olo, B2h, B2l, out, M, DD, DD);
  }
}

// Round 4
// 297.840 us; speedup vs baseline: 3.5358x; 1.2211x over previous
//
#include <hip/hip_runtime.h>
#include <hip/hip_bf16.h>
#include <math.h>

#define BB 2
#define SS 2048
#define DD 1024
#define HH 16
#define HDD 64

typedef float f32x4 __attribute__((ext_vector_type(4)));
typedef short s16x8 __attribute__((ext_vector_type(8)));
typedef unsigned short u16x8 __attribute__((ext_vector_type(8)));

__device__ inline unsigned short f2bf(float x) {
  unsigned u = __float_as_uint(x);
  unsigned r = u + 0x7fff + ((u >> 16) & 1);  // RNE
  return (unsigned short)(r >> 16);
}
__device__ inline float bf2f(unsigned short h) {
  return __uint_as_float(((unsigned)h) << 16);
}

// ---------------- pre-pass: split fp32 -> bf16 hi/lo (no transpose) --------
__global__ __launch_bounds__(256) void split_kernel(const float* __restrict__ X,
                                                    unsigned short* __restrict__ Xh,
                                                    unsigned short* __restrict__ Xl,
                                                    int n4) {
  int i = blockIdx.x * 256 + threadIdx.x;
  if (i >= n4) return;
  float4 v = ((const float4*)X)[i];
  ushort4 h, l;
  h.x = f2bf(v.x); l.x = f2bf(v.x - bf2f(h.x));
  h.y = f2bf(v.y); l.y = f2bf(v.y - bf2f(h.y));
  h.z = f2bf(v.z); l.z = f2bf(v.z - bf2f(h.z));
  h.w = f2bf(v.w); l.w = f2bf(v.w - bf2f(h.w));
  ((ushort4*)Xh)[i] = h;
  ((ushort4*)Xl)[i] = l;
}

// -------- pre-pass: split + transpose W[K][N] -> WT_h/WT_l [N][K] ----------
__global__ __launch_bounds__(256) void split_transpose_kernel(
    const float* __restrict__ W, unsigned short* __restrict__ WTh,
    unsigned short* __restrict__ WTl, int K, int N) {
  __shared__ float tile[64][65];
  const int k0 = blockIdx.y * 64, n0 = blockIdx.x * 64;
  const int t = threadIdx.x;
  const int c = t & 63, rq = t >> 6;
#pragma unroll
  for (int u = 0; u < 16; ++u) {
    int r = u * 4 + rq;
    tile[r][c] = W[(size_t)(k0 + r) * N + n0 + c];
  }
  __syncthreads();
#pragma unroll
  for (int u = 0; u < 16; ++u) {
    int nl = u * 4 + rq;
    float v = tile[c][nl];  // = W[k0+c][n0+nl]
    unsigned short h = f2bf(v);
    unsigned short l = f2bf(v - bf2f(h));
    size_t o = (size_t)(n0 + nl) * K + k0 + c;
    WTh[o] = h;
    WTl[o] = l;
  }
}

// ---------------- bf16x3 MFMA GEMM: C[M,N] = A[M,K] * B[K,N] ---------------
#define GLDS16(g, l)                                                        \
  __builtin_amdgcn_global_load_lds(                                         \
      (const __attribute__((address_space(1))) unsigned int*)(const void*)(g), \
      (__attribute__((address_space(3))) unsigned int*)(l), 16, 0, 0)

__global__ __launch_bounds__(256) void gemm_bf16x3_kernel(
    const unsigned short* __restrict__ Ah, const unsigned short* __restrict__ Al,
    const unsigned short* __restrict__ BTh, const unsigned short* __restrict__ BTl,
    float* __restrict__ C, int M, int N, int K) {
  __shared__ __align__(16) unsigned short As_h[128 * 64];
  __shared__ __align__(16) unsigned short As_l[128 * 64];
  __shared__ __align__(16) unsigned short Bs_h[128 * 64];
  __shared__ __align__(16) unsigned short Bs_l[128 * 64];

  const int t = threadIdx.x;
  const int bm = blockIdx.y * 128;
  const int bn = blockIdx.x * 128;
  const int w = t >> 6, lane = t & 63;
  const int wrow = (w >> 1) * 64, wcol = (w & 1) * 64;

  int tp[4], ldsoff[4];
  const unsigned short* pAh[4];
  const unsigned short* pAl[4];
  const unsigned short* pBh[4];
  const unsigned short* pBl[4];
#pragma unroll
  for (int cc = 0; cc < 4; ++cc) {
    tp[cc] = t + cc * 256;
    int srow = tp[cc] >> 3;
    int q = tp[cc] & 7;
    int gq = q ^ (srow & 7);
    ldsoff[cc] = tp[cc] * 8;
    pAh[cc] = Ah + (size_t)(bm + srow) * K + gq * 8;
    pAl[cc] = Al + (size_t)(bm + srow) * K + gq * 8;
    pBh[cc] = BTh + (size_t)(bn + srow) * K + gq * 8;
    pBl[cc] = BTl + (size_t)(bn + srow) * K + gq * 8;
  }

  f32x4 acc[4][4];
  const f32x4 z = {0.f, 0.f, 0.f, 0.f};
#pragma unroll
  for (int m = 0; m < 4; ++m)
#pragma unroll
    for (int n = 0; n < 4; ++n) acc[m][n] = z;

  for (int k0 = 0; k0 < K; k0 += 64) {
    __syncthreads();
#pragma unroll
    for (int cc = 0; cc < 4; ++cc) {
      GLDS16(pAh[cc] + k0, &As_h[ldsoff[cc]]);
      GLDS16(pAl[cc] + k0, &As_l[ldsoff[cc]]);
      GLDS16(pBh[cc] + k0, &Bs_h[ldsoff[cc]]);
      GLDS16(pBl[cc] + k0, &Bs_l[ldsoff[cc]]);
    }
    __syncthreads();

#pragma unroll
    for (int ks = 0; ks < 2; ++ks) {
      const int kq = ks * 4 + (lane >> 4);
      const int sw = (kq ^ (lane & 7)) * 8;
      s16x8 ah[4], al[4], bh[4], bl[4];
#pragma unroll
      for (int m = 0; m < 4; ++m) {
        int row = wrow + m * 16 + (lane & 15);
        int idx = row * 64 + sw;
        ah[m] = *(const s16x8*)&As_h[idx];
        al[m] = *(const s16x8*)&As_l[idx];
      }
#pragma unroll
      for (int n = 0; n < 4; ++n) {
        int row = wcol + n * 16 + (lane & 15);
        int idx = row * 64 + sw;
        bh[n] = *(const s16x8*)&Bs_h[idx];
        bl[n] = *(const s16x8*)&Bs_l[idx];
      }
#pragma unroll
      for (int m = 0; m < 4; ++m)
#pragma unroll
        for (int n = 0; n < 4; ++n) {
          acc[m][n] = __builtin_amdgcn_mfma_f32_16x16x32_bf16(ah[m], bh[n], acc[m][n], 0, 0, 0);
          acc[m][n] = __builtin_amdgcn_mfma_f32_16x16x32_bf16(ah[m], bl[n], acc[m][n], 0, 0, 0);
          acc[m][n] = __builtin_amdgcn_mfma_f32_16x16x32_bf16(al[m], bh[n], acc[m][n], 0, 0, 0);
        }
    }
  }

#pragma unroll
  for (int m = 0; m < 4; ++m)
#pragma unroll
    for (int n = 0; n < 4; ++n) {
      f32x4 v = acc[m][n];
      int col = bn + wcol + n * 16 + (lane & 15);
      int row0 = bm + wrow + m * 16 + (lane >> 4) * 4;
#pragma unroll
      for (int r = 0; r < 4; ++r) C[(size_t)(row0 + r) * N + col] = v[r];
    }
}

// -------- RoPE + split qkv -> Qhi/Qlo (x0.125*log2e), Khi/Klo, Vb ----------
__global__ __launch_bounds__(256) void rope_split_bf16_kernel(
    const float* __restrict__ qkv,
    const float* __restrict__ sin_q, const float* __restrict__ cos_q,
    const float* __restrict__ sin_k, const float* __restrict__ cos_k,
    unsigned short* __restrict__ Qhi, unsigned short* __restrict__ Qlo,
    unsigned short* __restrict__ Khi, unsigned short* __restrict__ Klo,
    unsigned short* __restrict__ Vb) {
  int idx = blockIdx.x * 256 + threadIdx.x;
  const int total = BB * SS * HH * (HDD / 2);
  if (idx >= total) return;
  const int dp = idx & 31;
  const int h  = (idx >> 5) & (HH - 1);
  const int s  = (idx >> 9) & (SS - 1);
  const int b  = idx >> 20;

  const float* row = qkv + (size_t)(b * SS + s) * (3 * DD);
  const size_t off = ((size_t)(b * HH + h) * SS + s) * HDD + dp;
  const float QSC = 0.125f * 1.44269504088896340736f;  // 1/sqrt(HD) * log2(e)

  {
    float c1 = cos_q[s * HDD + dp],      s1 = sin_q[s * HDD + dp];
    float c2 = cos_q[s * HDD + dp + 32], s2 = sin_q[s * HDD + dp + 32];
    float x1 = row[h * HDD + dp], x2 = row[h * HDD + dp + 32];
    float q1 = (x1 * c1 - x2 * s1) * QSC;
    float q2 = (x2 * c2 + x1 * s2) * QSC;
    unsigned short h1 = f2bf(q1), h2 = f2bf(q2);
    Qhi[off]      = h1; Qlo[off]      = f2bf(q1 - bf2f(h1));
    Qhi[off + 32] = h2; Qlo[off + 32] = f2bf(q2 - bf2f(h2));
  }
  {
    float c1 = cos_k[s * HDD + dp],      s1 = sin_k[s * HDD + dp];
    float c2 = cos_k[s * HDD + dp + 32], s2 = sin_k[s * HDD + dp + 32];
    float x1 = row[DD + h * HDD + dp], x2 = row[DD + h * HDD + dp + 32];
    float k1 = x1 * c1 - x2 * s1;
    float k2 = x2 * c2 + x1 * s2;
    unsigned short h1 = f2bf(k1), h2 = f2bf(k2);
    Khi[off]      = h1; Klo[off]      = f2bf(k1 - bf2f(h1));
    Khi[off + 32] = h2; Klo[off + 32] = f2bf(k2 - bf2f(h2));
  }
  Vb[off]      = f2bf(row[2 * DD + h * HDD + dp]);
  Vb[off + 32] = f2bf(row[2 * DD + h * HDD + dp + 32]);
}

// -------- V transpose: Vb [B,H,S,HD] bf16 -> Vt [B,H,HD,S] bf16 ------------
__global__ __launch_bounds__(256) void vtranspose_kernel(
    const unsigned short* __restrict__ Vb, unsigned short* __restrict__ Vt) {
  __shared__ unsigned short tile[64][72];
  const int s0 = blockIdx.x * 64;
  const int bh = blockIdx.y;
  const int t = threadIdx.x;
  const unsigned short* base = Vb + ((size_t)bh * SS + s0) * HDD;
#pragma unroll
  for (int c = 0; c < 2; ++c) {
    int G = t + c * 256;
    int r = G >> 3, g = G & 7;
    u16x8 v = *(const u16x8*)&base[r * HDD + g * 8];
    *(u16x8*)&tile[r][g * 8] = v;
  }
  __syncthreads();
#pragma unroll
  for (int c = 0; c < 2; ++c) {
    int G = t + c * 256;
    int d = G >> 3, gs = G & 7;
    u16x8 v;
#pragma unroll
    for (int j = 0; j < 8; ++j) v[j] = tile[gs * 8 + j][d];
    *(u16x8*)&Vt[((size_t)bh * HDD + d) * SS + s0 + gs * 8] = v;
  }
}

// ------------- causal flash attention, bf16 MFMA, paired Q-tiles -----------
// Block p handles Q-tiles qiA=31-p and qiB=p -> uniform 33 tile-computations.
// K/V double-buffered, prefetch next tile before computing current.
// exp2-domain softmax (log2e folded into Q); l via MFMA ones-trick; defer-max.

#define ATTN_TILE(QH, QL, OO, LS, MM, MASKED, CUR)                               \
  do {                                                                           \
    f32x4 sc[4];                                                                 \
    sc[0] = z; sc[1] = z; sc[2] = z; sc[3] = z;                                  \
    _Pragma("unroll")                                                            \
    for (int kc = 0; kc < 2; ++kc) {                                             \
      const int swz = ((kc * 4 + l4) ^ l7) * 8;                                  \
      _Pragma("unroll")                                                          \
      for (int n = 0; n < 4; ++n) {                                              \
        const int idx = (n * 16 + l15) * 64 + swz;                               \
        s16x8 kh = *(const s16x8*)&Ks_h[CUR][idx];                               \
        s16x8 kl = *(const s16x8*)&Ks_l[CUR][idx];                               \
        sc[n] = __builtin_amdgcn_mfma_f32_16x16x32_bf16(QH[kc], kh, sc[n], 0, 0, 0); \
        sc[n] = __builtin_amdgcn_mfma_f32_16x16x32_bf16(QL[kc], kh, sc[n], 0, 0, 0); \
        sc[n] = __builtin_amdgcn_mfma_f32_16x16x32_bf16(QH[kc], kl, sc[n], 0, 0, 0); \
      }                                                                          \
    }                                                                            \
    if (MASKED) {                                                                \
      _Pragma("unroll")                                                          \
      for (int n = 0; n < 4; ++n)                                                \
        _Pragma("unroll")                                                        \
        for (int r = 0; r < 4; ++r)                                              \
          if (n * 16 + l15 > w * 16 + l4 * 4 + r) sc[n][r] = -INFINITY;          \
    }                                                                            \
    float pm[4];                                                                 \
    _Pragma("unroll")                                                            \
    for (int r = 0; r < 4; ++r) {                                                \
      float tm = fmaxf(fmaxf(sc[0][r], sc[1][r]), fmaxf(sc[2][r], sc[3][r]));    \
      tm = fmaxf(tm, __shfl_xor(tm, 1));                                         \
      tm = fmaxf(tm, __shfl_xor(tm, 2));                                         \
      tm = fmaxf(tm, __shfl_xor(tm, 4));                                         \
      tm = fmaxf(tm, __shfl_xor(tm, 8));                                         \
      pm[r] = tm;                                                                 \
    }                                                                            \
    float growth = fmaxf(fmaxf(pm[0] - MM[0], pm[1] - MM[1]),                    \
                         fmaxf(pm[2] - MM[2], pm[3] - MM[3]));                   \
    if (!__all(growth <= 8.f)) {                                                 \
      _Pragma("unroll")                                                          \
      for (int r = 0; r < 4; ++r) {                                              \
        float mn = fmaxf(MM[r], pm[r]);                                          \
        float corr = __builtin_amdgcn_exp2f(MM[r] - mn);                         \
        MM[r] = mn;                                                              \
        OO[0][r] *= corr; OO[1][r] *= corr; OO[2][r] *= corr; OO[3][r] *= corr;  \
        LS[r] *= corr;                                                           \
      }                                                                          \
    }                                                                            \
    _Pragma("unroll")                                                            \
    for (int r = 0; r < 4; ++r) {                                                \
      const int pr = (w * 16 + l4 * 4 + r) * 72;                                 \
      _Pragma("unroll")                                                          \
      for (int n = 0; n < 4; ++n)                                                \
        Ps[pr + n * 16 + l15] = f2bf(__builtin_amdgcn_exp2f(sc[n][r] - MM[r]));  \
    }                                                                            \
    const int prow = (w * 16 + l15) * 72;                                        \
    _Pragma("unroll")                                                            \
    for (int c = 0; c < 2; ++c) {                                                \
      s16x8 pa = *(const s16x8*)&Ps[prow + c * 32 + 8 * l4];                     \
      const int swz = ((c * 4 + l4) ^ l7) * 8;                                   \
      _Pragma("unroll")                                                          \
      for (int n = 0; n < 4; ++n) {                                              \
        s16x8 vb = *(const s16x8*)&Vs[CUR][(n * 16 + l15) * 64 + swz];           \
        OO[n] = __builtin_amdgcn_mfma_f32_16x16x32_bf16(pa, vb, OO[n], 0, 0, 0); \
      }                                                                          \
      LS = __builtin_amdgcn_mfma_f32_16x16x32_bf16(pa, ones, LS, 0, 0, 0);       \
    }                                                                            \
  } while (0)

#define ATTN_EPI(OO, LS, QI)                                                     \
  do {                                                                           \
    _Pragma("unroll")                                                            \
    for (int r = 0; r < 4; ++r) {                                                \
      const float inv = 1.f / LS[r];                                             \
      const int orow = (QI) * 64 + w * 16 + l4 * 4 + r;                          \
      const size_t ob = ((size_t)b * SS + orow) * DD + h * HDD + l15;            \
      _Pragma("unroll")                                                          \
      for (int n = 0; n < 4; ++n) {                                              \
        float val = OO[n][r] * inv;                                              \
        unsigned short hh = f2bf(val);                                           \
        Ohi[ob + n * 16] = hh;                                                   \
        Olo[ob + n * 16] = f2bf(val - bf2f(hh));                                 \
      }                                                                          \
    }                                                                            \
  } while (0)

__global__ __launch_bounds__(256) void attn_mfma_kernel(
    const unsigned short* __restrict__ Qhi, const unsigned short* __restrict__ Qlo,
    const unsigned short* __restrict__ Khi_g, const unsigned short* __restrict__ Klo_g,
    const unsigned short* __restrict__ Vt_g,
    unsigned short* __restrict__ Ohi, unsigned short* __restrict__ Olo) {
  __shared__ __align__(16) unsigned short Ks_h[2][64 * 64];
  __shared__ __align__(16) unsigned short Ks_l[2][64 * 64];
  __shared__ __align__(16) unsigned short Vs[2][64 * 64];
  __shared__ __align__(16) unsigned short Ps[64 * 72];

  const int t = threadIdx.x;
  const int lane = t & 63;
  const int w = t >> 6;
  const int p = blockIdx.x;                 // 0..15
  const int qiA = 31 - p, qiB = p;          // long + short Q-tile: 33 tiles total
  const int bh = blockIdx.y;
  const int b = bh >> 4, h = bh & 15;
  const int l15 = lane & 15, l4 = lane >> 4, l7 = lane & 7;

  // Q fragments for both tiles (pre-scaled by 0.125*log2e in rope pass)
  s16x8 qhA[2], qlA[2], qhB[2], qlB[2];
  {
    const int rowA = qiA * 64 + w * 16 + l15;
    const unsigned short* qb = Qhi + ((size_t)bh * SS + rowA) * HDD + 8 * l4;
    const unsigned short* qc = Qlo + ((size_t)bh * SS + rowA) * HDD + 8 * l4;
    qhA[0] = *(const s16x8*)(qb);
    qhA[1] = *(const s16x8*)(qb + 32);
    qlA[0] = *(const s16x8*)(qc);
    qlA[1] = *(const s16x8*)(qc + 32);
    const int rowB = qiB * 64 + w * 16 + l15;
    const unsigned short* qd = Qhi + ((size_t)bh * SS + rowB) * HDD + 8 * l4;
    const unsigned short* qe = Qlo + ((size_t)bh * SS + rowB) * HDD + 8 * l4;
    qhB[0] = *(const s16x8*)(qd);
    qhB[1] = *(const s16x8*)(qd + 32);
    qlB[0] = *(const s16x8*)(qe);
    qlB[1] = *(const s16x8*)(qe + 32);
  }

  // staging maps: linear LDS dest, inverse-swizzled global source (rule #21)
  int lds[2];
  size_t koff[2], voff[2];
#pragma unroll
  for (int c = 0; c < 2; ++c) {
    int G = t + c * 256;
    int row = G >> 3, g = G & 7;
    int gs = g ^ (row & 7);
    lds[c] = G * 8;
    koff[c] = ((size_t)bh * SS + row) * HDD + gs * 8;
    voff[c] = ((size_t)bh * HDD + row) * SS + gs * 8;
  }

  const f32x4 z = {0.f, 0.f, 0.f, 0.f};
  f32x4 oA[4], oB[4], lsA = z, lsB = z;
#pragma unroll
  for (int n = 0; n < 4; ++n) { oA[n] = z; oB[n] = z; }
  float mA[4], mB[4];
#pragma unroll
  for (int r = 0; r < 4; ++r) { mA[r] = -INFINITY; mB[r] = -INFINITY; }

  const short one_bf = (short)0x3F80;
  const s16x8 ones = {one_bf, one_bf, one_bf, one_bf, one_bf, one_bf, one_bf, one_bf};

  // prologue: stage tile 0 into buffer 0
#pragma unroll
  for (int c = 0; c < 2; ++c) {
    GLDS16(Khi_g + koff[c], &Ks_h[0][lds[c]]);
    GLDS16(Klo_g + koff[c], &Ks_l[0][lds[c]]);
    GLDS16(Vt_g + voff[c], &Vs[0][lds[c]]);
  }
  __syncthreads();  // implicit vmcnt(0) drain before barrier

  int cur = 0;
  for (int kt = 0; kt <= qiA; ++kt) {
    if (kt < qiA) {  // prefetch next tile into the other buffer
      const size_t ka = (size_t)(kt + 1) * 64 * HDD;
      const size_t va = (size_t)(kt + 1) * 64;
      const int nxt = cur ^ 1;
#pragma unroll
      for (int c = 0; c < 2; ++c) {
        GLDS16(Khi_g + ka + koff[c], &Ks_h[nxt][lds[c]]);
        GLDS16(Klo_g + ka + koff[c], &Ks_l[nxt][lds[c]]);
        GLDS16(Vt_g + va + voff[c], &Vs[nxt][lds[c]]);
      }
    }
    ATTN_TILE(qhA, qlA, oA, lsA, mA, kt == qiA, cur);
    if (kt <= qiB) ATTN_TILE(qhB, qlB, oB, lsB, mB, kt == qiB, cur);
    __syncthreads();  // drains prefetch vmcnt; protects buffer swap
    cur ^= 1;
  }

  ATTN_EPI(oA, lsA, qiA);
  ATTN_EPI(oB, lsB, qiB);
}

extern "C" void kernel_launch(void* const* d_in, const int* in_sizes, int n_in,
                              void* d_out, int out_size, void* d_ws, size_t ws_size,
                              hipStream_t stream) {
  const float* query = (const float*)d_in[0];
  const float* sin_q = (const float*)d_in[1];
  const float* cos_q = (const float*)d_in[2];
  const float* sin_k = (const float*)d_in[3];
  const float* cos_k = (const float*)d_in[4];
  const float* w_in  = (const float*)d_in[5];
  const float* w_out = (const float*)d_in[6];
  float* out = (float*)d_out;

  const int M = BB * SS;  // 4096
  const size_t MD = (size_t)M * DD;

  unsigned char* ws = (unsigned char*)d_ws;
  size_t off = 0;
  float* qkv = (float*)(ws + off); off += MD * 3 * 4;
  unsigned short* Axh = (unsigned short*)(ws + off); off += MD * 2;
  unsigned short* Axl = (unsigned short*)(ws + off); off += MD * 2;
  unsigned short* B1h = (unsigned short*)(ws + off); off += (size_t)DD * 3 * DD * 2;
  unsigned short* B1l = (unsigned short*)(ws + off); off += (size_t)DD * 3 * DD * 2;
  unsigned short* B2h = (unsigned short*)(ws + off); off += (size_t)DD * DD * 2;
  unsigned short* B2l = (unsigned short*)(ws + off); off += (size_t)DD * DD * 2;
  unsigned short* Qhi = (unsigned short*)(ws + off); off += MD * 2;
  unsigned short* Qlo = (unsigned short*)(ws + off); off += MD * 2;
  unsigned short* Khi = (unsigned short*)(ws + off); off += MD * 2;
  unsigned short* Klo = (unsigned short*)(ws + off); off += MD * 2;
  unsigned short* Vb  = (unsigned short*)(ws + off); off += MD * 2;
  unsigned short* Vt  = (unsigned short*)(ws + off); off += MD * 2;
  unsigned short* Ohi = (unsigned short*)(ws + off); off += MD * 2;
  unsigned short* Olo = (unsigned short*)(ws + off); off += MD * 2;

  {  // pre-pass: operand splits
    int n4 = (int)(MD / 4);
    split_kernel<<<(n4 + 255) / 256, 256, 0, stream>>>(query, Axh, Axl, n4);
    split_transpose_kernel<<<dim3(3 * DD / 64, DD / 64), 256, 0, stream>>>(w_in, B1h, B1l, DD, 3 * DD);
    split_transpose_kernel<<<dim3(DD / 64, DD / 64), 256, 0, stream>>>(w_out, B2h, B2l, DD, DD);
  }
  {  // 1) fused QKV projection
    dim3 grid((3 * DD) / 128, M / 128);
    gemm_bf16x3_kernel<<<grid, 256, 0, stream>>>(Axh, Axl, B1h, B1l, qkv, M, 3 * DD, DD);
  }
  {  // 2) RoPE + split to bf16 hi/lo heads
    int total = BB * SS * HH * (HDD / 2);
    rope_split_bf16_kernel<<<(total + 255) / 256, 256, 0, stream>>>(
        qkv, sin_q, cos_q, sin_k, cos_k, Qhi, Qlo, Khi, Klo, Vb);
  }
  {  // 2b) V transpose for PV fragments
    vtranspose_kernel<<<dim3(SS / 64, BB * HH), 256, 0, stream>>>(Vb, Vt);
  }
  {  // 3) causal attention (MFMA, paired tiles, double-buffered)
    dim3 grid(SS / 128, BB * HH);
    attn_mfma_kernel<<<grid, 256, 0, stream>>>(Qhi, Qlo, Khi, Klo, Vt, Ohi, Olo);
  }
  {  // 4) output projection
    dim3 grid(DD / 128, M / 128);
    gemm_bf16x3_kernel<<<grid, 256, 0, stream>>>(Ohi, Olo, B2h, B2l, out, M, DD, DD);
  }
}

// Round 5
// 248.348 us; speedup vs baseline: 4.2404x; 1.1993x over previous
//
#include <hip/hip_runtime.h>
#include <hip/hip_bf16.h>
#include <math.h>

#define BB 2
#define SS 2048
#define DD 1024
#define HH 16
#define HDD 64

typedef float f32x4 __attribute__((ext_vector_type(4)));
typedef short s16x8 __attribute__((ext_vector_type(8)));
typedef unsigned short u16x8 __attribute__((ext_vector_type(8)));

__device__ inline unsigned short f2bf(float x) {
  unsigned u = __float_as_uint(x);
  unsigned r = u + 0x7fff + ((u >> 16) & 1);  // RNE
  return (unsigned short)(r >> 16);
}
__device__ inline float bf2f(unsigned short h) {
  return __uint_as_float(((unsigned)h) << 16);
}

// ---------------- pre-pass: cast fp32 -> bf16 (A operand, hi only) ---------
__global__ __launch_bounds__(256) void cast_bf16_kernel(const float* __restrict__ X,
                                                        unsigned short* __restrict__ Xb,
                                                        int n4) {
  int i = blockIdx.x * 256 + threadIdx.x;
  if (i >= n4) return;
  float4 v = ((const float4*)X)[i];
  ushort4 h;
  h.x = f2bf(v.x); h.y = f2bf(v.y); h.z = f2bf(v.z); h.w = f2bf(v.w);
  ((ushort4*)Xb)[i] = h;
}

// -------- pre-pass: split + transpose W[K][N] -> WT_h/WT_l [N][K] ----------
__global__ __launch_bounds__(256) void split_transpose_kernel(
    const float* __restrict__ W, unsigned short* __restrict__ WTh,
    unsigned short* __restrict__ WTl, int K, int N) {
  __shared__ float tile[64][65];
  const int k0 = blockIdx.y * 64, n0 = blockIdx.x * 64;
  const int t = threadIdx.x;
  const int c = t & 63, rq = t >> 6;
#pragma unroll
  for (int u = 0; u < 16; ++u) {
    int r = u * 4 + rq;
    tile[r][c] = W[(size_t)(k0 + r) * N + n0 + c];
  }
  __syncthreads();
#pragma unroll
  for (int u = 0; u < 16; ++u) {
    int nl = u * 4 + rq;
    float v = tile[c][nl];  // = W[k0+c][n0+nl]
    unsigned short h = f2bf(v);
    unsigned short l = f2bf(v - bf2f(h));
    size_t o = (size_t)(n0 + nl) * K + k0 + c;
    WTh[o] = h;
    WTl[o] = l;
  }
}

#define GLDS16(g, l)                                                        \
  __builtin_amdgcn_global_load_lds(                                         \
      (const __attribute__((address_space(1))) unsigned int*)(const void*)(g), \
      (__attribute__((address_space(3))) unsigned int*)(l), 16, 0, 0)

// =================== 2-term GEMM core (A bf16, B hi/lo) ====================
// Staging maps: linear LDS dest, inverse-swizzled global source (rule #21).
#define GEMM2T_PRE(Ab, BTh, BTl, Kdim)                                      \
  const int t = threadIdx.x;                                                \
  const int bm = blockIdx.y * 128;                                          \
  const int bn = blockIdx.x * 128;                                          \
  const int w = t >> 6, lane = t & 63;                                      \
  const int wrow = (w >> 1) * 64, wcol = (w & 1) * 64;                      \
  const int l15 = lane & 15, l4 = lane >> 4, l7 = lane & 7;                 \
  int ldsoff[4];                                                            \
  const unsigned short* pA[4];                                              \
  const unsigned short* pBh[4];                                             \
  const unsigned short* pBl[4];                                             \
  _Pragma("unroll")                                                         \
  for (int cc = 0; cc < 4; ++cc) {                                          \
    int tp = t + cc * 256;                                                  \
    int srow = tp >> 3;                                                     \
    int gq = (tp & 7) ^ (srow & 7);                                         \
    ldsoff[cc] = tp * 8;                                                    \
    pA[cc]  = (Ab)  + (size_t)(bm + srow) * (Kdim) + gq * 8;                \
    pBh[cc] = (BTh) + (size_t)(bn + srow) * (Kdim) + gq * 8;                \
    pBl[cc] = (BTl) + (size_t)(bn + srow) * (Kdim) + gq * 8;                \
  }                                                                         \
  f32x4 acc[4][4];                                                          \
  const f32x4 z = {0.f, 0.f, 0.f, 0.f};                                     \
  _Pragma("unroll")                                                         \
  for (int m = 0; m < 4; ++m)                                               \
    _Pragma("unroll")                                                       \
    for (int n = 0; n < 4; ++n) acc[m][n] = z;                              \
  for (int k0 = 0; k0 < (Kdim); k0 += 64) {                                 \
    __syncthreads();                                                        \
    _Pragma("unroll")                                                       \
    for (int cc = 0; cc < 4; ++cc) {                                        \
      GLDS16(pA[cc] + k0, &As_b[ldsoff[cc]]);                               \
      GLDS16(pBh[cc] + k0, &Bs_h[ldsoff[cc]]);                              \
      GLDS16(pBl[cc] + k0, &Bs_l[ldsoff[cc]]);                              \
    }                                                                       \
    __syncthreads();                                                        \
    _Pragma("unroll")                                                       \
    for (int ks = 0; ks < 2; ++ks) {                                        \
      const int sw = ((ks * 4 + l4) ^ l7) * 8;                              \
      s16x8 a[4], bh[4], bl[4];                                             \
      _Pragma("unroll")                                                     \
      for (int m = 0; m < 4; ++m)                                           \
        a[m] = *(const s16x8*)&As_b[(wrow + m * 16 + l15) * 64 + sw];       \
      _Pragma("unroll")                                                     \
      for (int n = 0; n < 4; ++n) {                                         \
        int idx = (wcol + n * 16 + l15) * 64 + sw;                          \
        bh[n] = *(const s16x8*)&Bs_h[idx];                                  \
        bl[n] = *(const s16x8*)&Bs_l[idx];                                  \
      }                                                                     \
      _Pragma("unroll")                                                     \
      for (int m = 0; m < 4; ++m)                                           \
        _Pragma("unroll")                                                   \
        for (int n = 0; n < 4; ++n) {                                       \
          acc[m][n] = __builtin_amdgcn_mfma_f32_16x16x32_bf16(a[m], bh[n], acc[m][n], 0, 0, 0); \
          acc[m][n] = __builtin_amdgcn_mfma_f32_16x16x32_bf16(a[m], bl[n], acc[m][n], 0, 0, 0); \
        }                                                                   \
    }                                                                       \
  }

// ---- GEMM1: fused QKV proj + RoPE + head-split + V-transpose epilogue -----
// C[M=4096][N=3072]; region = bn/1024 (0:q, 1:k, 2:v). Each 64-col warp
// window is exactly one head; rotation pair (d,d+32) = acc[m][n]/acc[m][n+2].
__global__ __launch_bounds__(256) void gemm_qkv_rope_kernel(
    const unsigned short* __restrict__ Ab,
    const unsigned short* __restrict__ BTh, const unsigned short* __restrict__ BTl,
    const float* __restrict__ sin_q, const float* __restrict__ cos_q,
    const float* __restrict__ sin_k, const float* __restrict__ cos_k,
    unsigned short* __restrict__ Qhi, unsigned short* __restrict__ Qlo,
    unsigned short* __restrict__ Khi, unsigned short* __restrict__ Vt) {
  __shared__ __align__(16) unsigned short As_b[128 * 64];
  __shared__ __align__(16) unsigned short Bs_h[128 * 64];
  __shared__ __align__(16) unsigned short Bs_l[128 * 64];
  GEMM2T_PRE(Ab, BTh, BTl, DD)

  const int region = bn >> 10;
  const int hloc = ((bn & 1023) + wcol) >> 6;
  const float QSC = 0.125f * 1.44269504088896340736f;  // 1/sqrt(HD) * log2(e)

  if (region == 0) {  // Q: rope, scale, split hi/lo
#pragma unroll
    for (int m = 0; m < 4; ++m) {
      const int row0 = bm + wrow + m * 16 + l4 * 4;
#pragma unroll
      for (int r = 0; r < 4; ++r) {
        const int row = row0 + r, b = row >> 11, s = row & 2047;
        const size_t ob = ((size_t)(b * HH + hloc) * SS + s) * HDD;
        const float* cq = cos_q + s * HDD;
        const float* sq = sin_q + s * HDD;
#pragma unroll
        for (int np = 0; np < 2; ++np) {
          const int d1 = np * 16 + l15;
          float x1 = acc[m][np][r], x2 = acc[m][np + 2][r];
          float q1 = (x1 * cq[d1] - x2 * sq[d1]) * QSC;
          float q2 = (x2 * cq[d1 + 32] + x1 * sq[d1 + 32]) * QSC;
          unsigned short h1 = f2bf(q1), h2 = f2bf(q2);
          Qhi[ob + d1] = h1;      Qlo[ob + d1] = f2bf(q1 - bf2f(h1));
          Qhi[ob + d1 + 32] = h2; Qlo[ob + d1 + 32] = f2bf(q2 - bf2f(h2));
        }
      }
    }
  } else if (region == 1) {  // K: rope, single bf16
#pragma unroll
    for (int m = 0; m < 4; ++m) {
      const int row0 = bm + wrow + m * 16 + l4 * 4;
#pragma unroll
      for (int r = 0; r < 4; ++r) {
        const int row = row0 + r, b = row >> 11, s = row & 2047;
        const size_t ob = ((size_t)(b * HH + hloc) * SS + s) * HDD;
        const float* ck = cos_k + s * HDD;
        const float* sk = sin_k + s * HDD;
#pragma unroll
        for (int np = 0; np < 2; ++np) {
          const int d1 = np * 16 + l15;
          float x1 = acc[m][np][r], x2 = acc[m][np + 2][r];
          Khi[ob + d1]      = f2bf(x1 * ck[d1] - x2 * sk[d1]);
          Khi[ob + d1 + 32] = f2bf(x2 * ck[d1 + 32] + x1 * sk[d1 + 32]);
        }
      }
    }
  } else {  // V: transpose to [B,H,HD,S], coalesced ushort4 along s
#pragma unroll
    for (int m = 0; m < 4; ++m) {
      const int row0 = bm + wrow + m * 16 + l4 * 4;
      const int b = row0 >> 11, s0 = row0 & 2047;
#pragma unroll
      for (int n = 0; n < 4; ++n) {
        const int d = n * 16 + l15;
        ushort4 v4;
        v4.x = f2bf(acc[m][n][0]);
        v4.y = f2bf(acc[m][n][1]);
        v4.z = f2bf(acc[m][n][2]);
        v4.w = f2bf(acc[m][n][3]);
        *(ushort4*)&Vt[((size_t)(b * HH + hloc) * HDD + d) * SS + s0] = v4;
      }
    }
  }
}

// ---- GEMM2: output projection, fp32 C ----
__global__ __launch_bounds__(256) void gemm_out_kernel(
    const unsigned short* __restrict__ Ab,
    const unsigned short* __restrict__ BTh, const unsigned short* __restrict__ BTl,
    float* __restrict__ C) {
  __shared__ __align__(16) unsigned short As_b[128 * 64];
  __shared__ __align__(16) unsigned short Bs_h[128 * 64];
  __shared__ __align__(16) unsigned short Bs_l[128 * 64];
  GEMM2T_PRE(Ab, BTh, BTl, DD)

#pragma unroll
  for (int m = 0; m < 4; ++m)
#pragma unroll
    for (int n = 0; n < 4; ++n) {
      f32x4 v = acc[m][n];
      int col = bn + wcol + n * 16 + l15;
      int row0 = bm + wrow + m * 16 + l4 * 4;
#pragma unroll
      for (int r = 0; r < 4; ++r) C[(size_t)(row0 + r) * DD + col] = v[r];
    }
}

// ------------- causal flash attention, bf16 MFMA, paired Q-tiles -----------
// Q hi/lo in regs (2-MFMA QK^T), K single bf16 in LDS, V transposed in LDS.
// exp2-domain softmax; l via MFMA ones-trick; defer-max; T5 setprio.

#define ATTN_TILE(QH, QL, OO, LS, MM, MASKED, CUR)                               \
  do {                                                                           \
    f32x4 sc[4];                                                                 \
    sc[0] = z; sc[1] = z; sc[2] = z; sc[3] = z;                                  \
    __builtin_amdgcn_s_setprio(1);                                               \
    _Pragma("unroll")                                                            \
    for (int kc = 0; kc < 2; ++kc) {                                             \
      const int swz = ((kc * 4 + l4) ^ l7) * 8;                                  \
      _Pragma("unroll")                                                          \
      for (int n = 0; n < 4; ++n) {                                              \
        const int idx = (n * 16 + l15) * 64 + swz;                               \
        s16x8 kh = *(const s16x8*)&Ks[CUR][idx];                                 \
        sc[n] = __builtin_amdgcn_mfma_f32_16x16x32_bf16(QH[kc], kh, sc[n], 0, 0, 0); \
        sc[n] = __builtin_amdgcn_mfma_f32_16x16x32_bf16(QL[kc], kh, sc[n], 0, 0, 0); \
      }                                                                          \
    }                                                                            \
    __builtin_amdgcn_s_setprio(0);                                               \
    if (MASKED) {                                                                \
      _Pragma("unroll")                                                          \
      for (int n = 0; n < 4; ++n)                                                \
        _Pragma("unroll")                                                        \
        for (int r = 0; r < 4; ++r)                                              \
          if (n * 16 + l15 > w * 16 + l4 * 4 + r) sc[n][r] = -INFINITY;          \
    }                                                                            \
    float pm[4];                                                                 \
    _Pragma("unroll")                                                            \
    for (int r = 0; r < 4; ++r) {                                                \
      float tm = fmaxf(fmaxf(sc[0][r], sc[1][r]), fmaxf(sc[2][r], sc[3][r]));    \
      tm = fmaxf(tm, __shfl_xor(tm, 1));                                         \
      tm = fmaxf(tm, __shfl_xor(tm, 2));                                         \
      tm = fmaxf(tm, __shfl_xor(tm, 4));                                         \
      tm = fmaxf(tm, __shfl_xor(tm, 8));                                         \
      pm[r] = tm;                                                                 \
    }                                                                            \
    float growth = fmaxf(fmaxf(pm[0] - MM[0], pm[1] - MM[1]),                    \
                         fmaxf(pm[2] - MM[2], pm[3] - MM[3]));                   \
    if (!__all(growth <= 8.f)) {                                                 \
      _Pragma("unroll")                                                          \
      for (int r = 0; r < 4; ++r) {                                              \
        float mn = fmaxf(MM[r], pm[r]);                                          \
        float corr = __builtin_amdgcn_exp2f(MM[r] - mn);                         \
        MM[r] = mn;                                                              \
        OO[0][r] *= corr; OO[1][r] *= corr; OO[2][r] *= corr; OO[3][r] *= corr;  \
        LS[r] *= corr;                                                           \
      }                                                                          \
    }                                                                            \
    _Pragma("unroll")                                                            \
    for (int r = 0; r < 4; ++r) {                                                \
      const int pr = (w * 16 + l4 * 4 + r) * 72;                                 \
      _Pragma("unroll")                                                          \
      for (int n = 0; n < 4; ++n)                                                \
        Ps[pr + n * 16 + l15] = f2bf(__builtin_amdgcn_exp2f(sc[n][r] - MM[r]));  \
    }                                                                            \
    const int prow = (w * 16 + l15) * 72;                                        \
    __builtin_amdgcn_s_setprio(1);                                               \
    _Pragma("unroll")                                                            \
    for (int c = 0; c < 2; ++c) {                                                \
      s16x8 pa = *(const s16x8*)&Ps[prow + c * 32 + 8 * l4];                     \
      const int swz = ((c * 4 + l4) ^ l7) * 8;                                   \
      _Pragma("unroll")                                                          \
      for (int n = 0; n < 4; ++n) {                                              \
        s16x8 vb = *(const s16x8*)&Vs[CUR][(n * 16 + l15) * 64 + swz];           \
        OO[n] = __builtin_amdgcn_mfma_f32_16x16x32_bf16(pa, vb, OO[n], 0, 0, 0); \
      }                                                                          \
      LS = __builtin_amdgcn_mfma_f32_16x16x32_bf16(pa, ones, LS, 0, 0, 0);       \
    }                                                                            \
    __builtin_amdgcn_s_setprio(0);                                               \
  } while (0)

#define ATTN_EPI(OO, LS, QI)                                                     \
  do {                                                                           \
    _Pragma("unroll")                                                            \
    for (int r = 0; r < 4; ++r) {                                                \
      const float inv = 1.f / LS[r];                                             \
      const int orow = (QI) * 64 + w * 16 + l4 * 4 + r;                          \
      const size_t ob = ((size_t)b * SS + orow) * DD + h * HDD + l15;            \
      _Pragma("unroll")                                                          \
      for (int n = 0; n < 4; ++n)                                                \
        Ohi[ob + n * 16] = f2bf(OO[n][r] * inv);                                 \
    }                                                                            \
  } while (0)

__global__ __launch_bounds__(256) void attn_mfma_kernel(
    const unsigned short* __restrict__ Qhi, const unsigned short* __restrict__ Qlo,
    const unsigned short* __restrict__ Khi_g, const unsigned short* __restrict__ Vt_g,
    unsigned short* __restrict__ Ohi) {
  __shared__ __align__(16) unsigned short Ks[2][64 * 64];
  __shared__ __align__(16) unsigned short Vs[2][64 * 64];
  __shared__ __align__(16) unsigned short Ps[64 * 72];

  const int t = threadIdx.x;
  const int lane = t & 63;
  const int w = t >> 6;
  const int p = blockIdx.x;                 // 0..15
  const int qiA = 31 - p, qiB = p;          // long + short tile: 33 total
  const int bh = blockIdx.y;
  const int b = bh >> 4, h = bh & 15;
  const int l15 = lane & 15, l4 = lane >> 4, l7 = lane & 7;

  s16x8 qhA[2], qlA[2], qhB[2], qlB[2];
  {
    const int rowA = qiA * 64 + w * 16 + l15;
    const unsigned short* qb = Qhi + ((size_t)bh * SS + rowA) * HDD + 8 * l4;
    const unsigned short* qc = Qlo + ((size_t)bh * SS + rowA) * HDD + 8 * l4;
    qhA[0] = *(const s16x8*)(qb);
    qhA[1] = *(const s16x8*)(qb + 32);
    qlA[0] = *(const s16x8*)(qc);
    qlA[1] = *(const s16x8*)(qc + 32);
    const int rowB = qiB * 64 + w * 16 + l15;
    const unsigned short* qd = Qhi + ((size_t)bh * SS + rowB) * HDD + 8 * l4;
    const unsigned short* qe = Qlo + ((size_t)bh * SS + rowB) * HDD + 8 * l4;
    qhB[0] = *(const s16x8*)(qd);
    qhB[1] = *(const s16x8*)(qd + 32);
    qlB[0] = *(const s16x8*)(qe);
    qlB[1] = *(const s16x8*)(qe + 32);
  }

  int lds[2];
  size_t koff[2], voff[2];
#pragma unroll
  for (int c = 0; c < 2; ++c) {
    int G = t + c * 256;
    int row = G >> 3, g = G & 7;
    int gs = g ^ (row & 7);
    lds[c] = G * 8;
    koff[c] = ((size_t)bh * SS + row) * HDD + gs * 8;
    voff[c] = ((size_t)bh * HDD + row) * SS + gs * 8;
  }

  const f32x4 z = {0.f, 0.f, 0.f, 0.f};
  f32x4 oA[4], oB[4], lsA = z, lsB = z;
#pragma unroll
  for (int n = 0; n < 4; ++n) { oA[n] = z; oB[n] = z; }
  float mA[4], mB[4];
#pragma unroll
  for (int r = 0; r < 4; ++r) { mA[r] = -INFINITY; mB[r] = -INFINITY; }

  const short one_bf = (short)0x3F80;
  const s16x8 ones = {one_bf, one_bf, one_bf, one_bf, one_bf, one_bf, one_bf, one_bf};

#pragma unroll
  for (int c = 0; c < 2; ++c) {
    GLDS16(Khi_g + koff[c], &Ks[0][lds[c]]);
    GLDS16(Vt_g + voff[c], &Vs[0][lds[c]]);
  }
  __syncthreads();

  int cur = 0;
  for (int kt = 0; kt <= qiA; ++kt) {
    if (kt < qiA) {
      const size_t ka = (size_t)(kt + 1) * 64 * HDD;
      const size_t va = (size_t)(kt + 1) * 64;
      const int nxt = cur ^ 1;
#pragma unroll
      for (int c = 0; c < 2; ++c) {
        GLDS16(Khi_g + ka + koff[c], &Ks[nxt][lds[c]]);
        GLDS16(Vt_g + va + voff[c], &Vs[nxt][lds[c]]);
      }
    }
    ATTN_TILE(qhA, qlA, oA, lsA, mA, kt == qiA, cur);
    if (kt <= qiB) ATTN_TILE(qhB, qlB, oB, lsB, mB, kt == qiB, cur);
    __syncthreads();
    cur ^= 1;
  }

  ATTN_EPI(oA, lsA, qiA);
  ATTN_EPI(oB, lsB, qiB);
}

extern "C" void kernel_launch(void* const* d_in, const int* in_sizes, int n_in,
                              void* d_out, int out_size, void* d_ws, size_t ws_size,
                              hipStream_t stream) {
  const float* query = (const float*)d_in[0];
  const float* sin_q = (const float*)d_in[1];
  const float* cos_q = (const float*)d_in[2];
  const float* sin_k = (const float*)d_in[3];
  const float* cos_k = (const float*)d_in[4];
  const float* w_in  = (const float*)d_in[5];
  const float* w_out = (const float*)d_in[6];
  float* out = (float*)d_out;

  const int M = BB * SS;  // 4096
  const size_t MD = (size_t)M * DD;

  unsigned char* ws = (unsigned char*)d_ws;
  size_t off = 0;
  unsigned short* Qb  = (unsigned short*)(ws + off); off += MD * 2;              // query bf16
  unsigned short* B1h = (unsigned short*)(ws + off); off += (size_t)DD * 3 * DD * 2;
  unsigned short* B1l = (unsigned short*)(ws + off); off += (size_t)DD * 3 * DD * 2;
  unsigned short* B2h = (unsigned short*)(ws + off); off += (size_t)DD * DD * 2;
  unsigned short* B2l = (unsigned short*)(ws + off); off += (size_t)DD * DD * 2;
  unsigned short* Qhi = (unsigned short*)(ws + off); off += MD * 2;
  unsigned short* Qlo = (unsigned short*)(ws + off); off += MD * 2;
  unsigned short* Khi = (unsigned short*)(ws + off); off += MD * 2;
  unsigned short* Vt  = (unsigned short*)(ws + off); off += MD * 2;
  unsigned short* Ohi = (unsigned short*)(ws + off); off += MD * 2;

  {  // pre-pass: A cast + weight splits
    int n4 = (int)(MD / 4);
    cast_bf16_kernel<<<(n4 + 255) / 256, 256, 0, stream>>>(query, Qb, n4);
    split_transpose_kernel<<<dim3(3 * DD / 64, DD / 64), 256, 0, stream>>>(w_in, B1h, B1l, DD, 3 * DD);
    split_transpose_kernel<<<dim3(DD / 64, DD / 64), 256, 0, stream>>>(w_out, B2h, B2l, DD, DD);
  }
  {  // 1) fused QKV projection + RoPE + head-split + V-transpose
    dim3 grid((3 * DD) / 128, M / 128);
    gemm_qkv_rope_kernel<<<grid, 256, 0, stream>>>(
        Qb, B1h, B1l, sin_q, cos_q, sin_k, cos_k, Qhi, Qlo, Khi, Vt);
  }
  {  // 2) causal attention (MFMA, paired tiles, double-buffered)
    dim3 grid(SS / 128, BB * HH);
    attn_mfma_kernel<<<grid, 256, 0, stream>>>(Qhi, Qlo, Khi, Vt, Ohi);
  }
  {  // 3) output projection
    dim3 grid(DD / 128, M / 128);
    gemm_out_kernel<<<grid, 256, 0, stream>>>(Ohi, B2h, B2l, out);
  }
}